// Round 1
// baseline (3489.225 us; speedup 1.0000x reference)
//
#include <hip/hip_runtime.h>
#include <math.h>

typedef __attribute__((ext_vector_type(4))) float f4;

#define H 128
#define NLAYERS 3
#define FLIG 16
#define FPOC 27
#define NLIG 20000
#define NPOC 30000
#define ELIG 160000
#define EPOC 240000
#define NB 8

__device__ __forceinline__ float silu_f(float v){ return v / (1.0f + __expf(-v)); }

// ---------------- embedding: h = x @ W + b ----------------
__global__ void k_embed(const float* __restrict__ x, const float* __restrict__ W,
                        const float* __restrict__ b, float* __restrict__ h,
                        int N, int F){
  int tid = threadIdx.x;
  int n = blockIdx.x*2 + (tid >> 7);
  int j = tid & 127;
  if (n >= N) return;
  float acc = b[j];
  for (int k = 0; k < F; k++) acc += x[n*F + k] * W[k*H + j];
  h[(size_t)n*H + j] = acc;
}

// ---------------- degree histogram ----------------
__global__ void k_hist(const int* __restrict__ dst, int* __restrict__ deg, int E){
  int e = blockIdx.x*256 + threadIdx.x;
  if (e < E) atomicAdd(&deg[dst[e]], 1);
}

// ---------------- single-block exclusive scan ----------------
__global__ void k_scan(const int* __restrict__ deg, int* __restrict__ offs, int N, int E){
  __shared__ int part[1024];
  int t = threadIdx.x;
  int chunk = (N + 1023) >> 10;
  int b0 = t*chunk;
  int b1 = b0 + chunk; if (b1 > N) b1 = N;
  int s = 0;
  for (int i = b0; i < b1; i++) s += deg[i];
  part[t] = s;
  __syncthreads();
  for (int off = 1; off < 1024; off <<= 1){
    int v = (t >= off) ? part[t-off] : 0;
    __syncthreads();
    part[t] += v;
    __syncthreads();
  }
  int run = part[t] - s;   // exclusive
  for (int i = b0; i < b1; i++){ offs[i] = run; run += deg[i]; }
  if (t == 1023) offs[N] = E;
}

// ---------------- counting-sort scatter ----------------
__global__ void k_sort(const int* __restrict__ src, const int* __restrict__ dst,
                       const int* __restrict__ offs, int* __restrict__ cur,
                       int* __restrict__ ssrc, int* __restrict__ sdst, int E){
  int e = blockIdx.x*256 + threadIdx.x;
  if (e < E){
    int d = dst[e];
    int p = offs[d] + atomicAdd(&cur[d], 1);
    ssrc[p] = src[e];
    sdst[p] = d;
  }
}

// ---------------- fused edge MLP + scatter ----------------
// 32 edges per block, 256 threads. GEMM micro-tile 4e x 4j per thread.
__global__ __launch_bounds__(256, 3) void k_edge(
    const float* __restrict__ h, const float* __restrict__ x,
    const int* __restrict__ ssrc, const int* __restrict__ sdst,
    const float* __restrict__ We1, const float* __restrict__ be1,
    const float* __restrict__ We2, const float* __restrict__ be2,
    const float* __restrict__ Wx, const float* __restrict__ bxp,
    float* __restrict__ agg_m, float* __restrict__ agg_x)
{
  __shared__ __align__(16) float ein[32][260];   // e_in: [hd(128) | hs(128) | d2] per edge
  __shared__ __align__(16) float mt[32][132];    // silu(GEMM1) output
  __shared__ float relS[32][3];
  __shared__ int sI[32], dI[32];

  int tid = threadIdx.x;
  int e0 = blockIdx.x * 32;

  if (tid < 32){ sI[tid] = ssrc[e0+tid]; dI[tid] = sdst[e0+tid]; }
  __syncthreads();

  if (tid < 32){
    int s = sI[tid], d = dI[tid];
    float rx = x[d*3+0] - x[s*3+0];
    float ry = x[d*3+1] - x[s*3+1];
    float rz = x[d*3+2] - x[s*3+2];
    relS[tid][0] = rx; relS[tid][1] = ry; relS[tid][2] = rz;
    ein[tid][256] = rx*rx + ry*ry + rz*rz;
  }
  {
    int ge = tid >> 3, gp = tid & 7;
    int row = (gp < 4) ? dI[ge] : sI[ge];
    int cbase = (gp & 3) * 32;
    const f4* s4 = (const f4*)(h + (size_t)row*H + cbase);
    int dcol = ((gp < 4) ? 0 : 128) + cbase;
    f4* d4 = (f4*)&ein[ge][dcol];
    #pragma unroll
    for (int i = 0; i < 8; i++) d4[i] = s4[i];
  }
  __syncthreads();

  int jg = tid & 31, eg = tid >> 5;
  int j0 = jg*4, el = eg*4;

  float acc[4][4];
  #pragma unroll
  for (int i = 0; i < 4; i++)
    #pragma unroll
    for (int jj = 0; jj < 4; jj++) acc[i][jj] = 0.f;

  // GEMM1: K = 257 (256 main + d2 tail)
  for (int k = 0; k < 256; k += 4){
    f4 A0 = *(const f4*)&ein[el+0][k];
    f4 A1 = *(const f4*)&ein[el+1][k];
    f4 A2 = *(const f4*)&ein[el+2][k];
    f4 A3 = *(const f4*)&ein[el+3][k];
    f4 B0 = *(const f4*)(We1 + (size_t)(k+0)*H + j0);
    f4 B1 = *(const f4*)(We1 + (size_t)(k+1)*H + j0);
    f4 B2 = *(const f4*)(We1 + (size_t)(k+2)*H + j0);
    f4 B3 = *(const f4*)(We1 + (size_t)(k+3)*H + j0);
    #pragma unroll
    for (int jj = 0; jj < 4; jj++){
      acc[0][jj] += A0[0]*B0[jj] + A0[1]*B1[jj] + A0[2]*B2[jj] + A0[3]*B3[jj];
      acc[1][jj] += A1[0]*B0[jj] + A1[1]*B1[jj] + A1[2]*B2[jj] + A1[3]*B3[jj];
      acc[2][jj] += A2[0]*B0[jj] + A2[1]*B1[jj] + A2[2]*B2[jj] + A2[3]*B3[jj];
      acc[3][jj] += A3[0]*B0[jj] + A3[1]*B1[jj] + A3[2]*B2[jj] + A3[3]*B3[jj];
    }
  }
  {
    f4 B = *(const f4*)(We1 + (size_t)256*H + j0);
    #pragma unroll
    for (int i = 0; i < 4; i++){
      float a = ein[el+i][256];
      #pragma unroll
      for (int jj = 0; jj < 4; jj++) acc[i][jj] += a * B[jj];
    }
  }
  {
    f4 be = *(const f4*)(be1 + j0);
    #pragma unroll
    for (int i = 0; i < 4; i++){
      f4 m;
      #pragma unroll
      for (int jj = 0; jj < 4; jj++) m[jj] = silu_f(acc[i][jj] + be[jj]);
      *(f4*)&mt[el+i][j0] = m;
    }
  }
  __syncthreads();

  // GEMM2: K = 128
  #pragma unroll
  for (int i = 0; i < 4; i++)
    #pragma unroll
    for (int jj = 0; jj < 4; jj++) acc[i][jj] = 0.f;

  for (int k = 0; k < 128; k += 4){
    f4 A0 = *(const f4*)&mt[el+0][k];
    f4 A1 = *(const f4*)&mt[el+1][k];
    f4 A2 = *(const f4*)&mt[el+2][k];
    f4 A3 = *(const f4*)&mt[el+3][k];
    f4 B0 = *(const f4*)(We2 + (size_t)(k+0)*H + j0);
    f4 B1 = *(const f4*)(We2 + (size_t)(k+1)*H + j0);
    f4 B2 = *(const f4*)(We2 + (size_t)(k+2)*H + j0);
    f4 B3 = *(const f4*)(We2 + (size_t)(k+3)*H + j0);
    #pragma unroll
    for (int jj = 0; jj < 4; jj++){
      acc[0][jj] += A0[0]*B0[jj] + A0[1]*B1[jj] + A0[2]*B2[jj] + A0[3]*B3[jj];
      acc[1][jj] += A1[0]*B0[jj] + A1[1]*B1[jj] + A1[2]*B2[jj] + A1[3]*B3[jj];
      acc[2][jj] += A2[0]*B0[jj] + A2[1]*B1[jj] + A2[2]*B2[jj] + A2[3]*B3[jj];
      acc[3][jj] += A3[0]*B0[jj] + A3[1]*B1[jj] + A3[2]*B2[jj] + A3[3]*B3[jj];
    }
  }

  float m2[4][4];
  {
    f4 b2 = *(const f4*)(be2 + j0);
    #pragma unroll
    for (int i = 0; i < 4; i++)
      #pragma unroll
      for (int jj = 0; jj < 4; jj++) m2[i][jj] = silu_f(acc[i][jj] + b2[jj]);
  }

  // coef = m2 @ Wx + bx  (reduce over the 32 jg lanes)
  f4 wx = *(const f4*)(Wx + j0);
  float part[4];
  #pragma unroll
  for (int i = 0; i < 4; i++)
    part[i] = m2[i][0]*wx[0] + m2[i][1]*wx[1] + m2[i][2]*wx[2] + m2[i][3]*wx[3];
  #pragma unroll
  for (int off = 16; off >= 1; off >>= 1){
    #pragma unroll
    for (int i = 0; i < 4; i++) part[i] += __shfl_xor(part[i], off, 64);
  }

  // stash m2 in LDS (overlay ein space; all ein reads are done)
  float (*m2t)[132] = (float(*)[132])&ein[0][0];
  #pragma unroll
  for (int i = 0; i < 4; i++){
    f4 mv;
    #pragma unroll
    for (int jj = 0; jj < 4; jj++) mv[jj] = m2[i][jj];
    *(f4*)&m2t[el+i][j0] = mv;
  }

  if (jg == 0){
    float bxv = bxp[0];
    #pragma unroll
    for (int i = 0; i < 4; i++){
      int e = el + i;
      float cf = part[i] + bxv;
      int d = dI[e];
      atomicAdd(&agg_x[(size_t)d*3 + 0], relS[e][0]*cf);
      atomicAdd(&agg_x[(size_t)d*3 + 1], relS[e][1]*cf);
      atomicAdd(&agg_x[(size_t)d*3 + 2], relS[e][2]*cf);
    }
  }
  __syncthreads();

  // segmented scatter of m2 into agg_m (edges sorted by dst -> few atomics)
  {
    int j = tid & 127, hh = tid >> 7;
    int eb = hh * 16;
    float s = 0.f;
    int run = dI[eb];
    for (int e = eb; e < eb + 16; e++){
      int d = dI[e];
      if (d != run){ atomicAdd(&agg_m[(size_t)run*H + j], s); s = 0.f; run = d; }
      s += m2t[e][j];
    }
    atomicAdd(&agg_m[(size_t)run*H + j], s);
  }
}

// ---------------- fused node update ----------------
__global__ __launch_bounds__(256) void k_node(
    float* __restrict__ h, float* __restrict__ x,
    const float* __restrict__ agg_m, const float* __restrict__ agg_x,
    const int* __restrict__ degi,
    const float* __restrict__ Wh1, const float* __restrict__ bh1,
    const float* __restrict__ Wh2, const float* __restrict__ bh2)
{
  __shared__ __align__(16) float hc[16][260];  // [h | agg_m]
  __shared__ __align__(16) float u1[16][132];
  int tid = threadIdx.x;
  int n0b = blockIdx.x * 16;

  if (tid < 48){
    int nn = tid / 3, c = tid - nn*3;
    int gn = n0b + nn;
    float dv = (float)degi[gn]; if (dv < 1.f) dv = 1.f;
    x[(size_t)gn*3 + c] += agg_x[(size_t)gn*3 + c] / dv;
  }
  {
    int ge = tid >> 4, gp = tid & 15;
    int gn = n0b + ge;
    const float* sp = (gp < 8) ? (h + (size_t)gn*H + gp*16)
                               : (agg_m + (size_t)gn*H + (gp-8)*16);
    f4* d4 = (f4*)&hc[ge][gp*16];
    const f4* s4 = (const f4*)sp;
    #pragma unroll
    for (int i = 0; i < 4; i++) d4[i] = s4[i];
  }
  __syncthreads();

  int jg = tid & 31, ng = tid >> 5;
  int j0 = jg*4, n0 = ng*2;

  float acc[2][4];
  #pragma unroll
  for (int i = 0; i < 2; i++)
    #pragma unroll
    for (int jj = 0; jj < 4; jj++) acc[i][jj] = 0.f;

  for (int k = 0; k < 256; k += 4){
    f4 A0 = *(const f4*)&hc[n0+0][k];
    f4 A1 = *(const f4*)&hc[n0+1][k];
    f4 B0 = *(const f4*)(Wh1 + (size_t)(k+0)*H + j0);
    f4 B1 = *(const f4*)(Wh1 + (size_t)(k+1)*H + j0);
    f4 B2 = *(const f4*)(Wh1 + (size_t)(k+2)*H + j0);
    f4 B3 = *(const f4*)(Wh1 + (size_t)(k+3)*H + j0);
    #pragma unroll
    for (int jj = 0; jj < 4; jj++){
      acc[0][jj] += A0[0]*B0[jj] + A0[1]*B1[jj] + A0[2]*B2[jj] + A0[3]*B3[jj];
      acc[1][jj] += A1[0]*B0[jj] + A1[1]*B1[jj] + A1[2]*B2[jj] + A1[3]*B3[jj];
    }
  }
  {
    f4 b1 = *(const f4*)(bh1 + j0);
    #pragma unroll
    for (int i = 0; i < 2; i++){
      f4 u;
      #pragma unroll
      for (int jj = 0; jj < 4; jj++) u[jj] = silu_f(acc[i][jj] + b1[jj]);
      *(f4*)&u1[n0+i][j0] = u;
    }
  }
  __syncthreads();

  float acc2[2][4];
  #pragma unroll
  for (int i = 0; i < 2; i++)
    #pragma unroll
    for (int jj = 0; jj < 4; jj++) acc2[i][jj] = 0.f;

  for (int k = 0; k < 128; k += 4){
    f4 A0 = *(const f4*)&u1[n0+0][k];
    f4 A1 = *(const f4*)&u1[n0+1][k];
    f4 B0 = *(const f4*)(Wh2 + (size_t)(k+0)*H + j0);
    f4 B1 = *(const f4*)(Wh2 + (size_t)(k+1)*H + j0);
    f4 B2 = *(const f4*)(Wh2 + (size_t)(k+2)*H + j0);
    f4 B3 = *(const f4*)(Wh2 + (size_t)(k+3)*H + j0);
    #pragma unroll
    for (int jj = 0; jj < 4; jj++){
      acc2[0][jj] += A0[0]*B0[jj] + A0[1]*B1[jj] + A0[2]*B2[jj] + A0[3]*B3[jj];
      acc2[1][jj] += A1[0]*B0[jj] + A1[1]*B1[jj] + A1[2]*B2[jj] + A1[3]*B3[jj];
    }
  }
  {
    f4 b2 = *(const f4*)(bh2 + j0);
    #pragma unroll
    for (int i = 0; i < 2; i++){
      f4 hv;
      #pragma unroll
      for (int jj = 0; jj < 4; jj++) hv[jj] = hc[n0+i][j0+jj] + acc2[i][jj] + b2[jj];
      *(f4*)(h + (size_t)(n0b+n0+i)*H + j0) = hv;
    }
  }
}

// ---------------- head weight transpose prep ----------------
__global__ void k_prep(const float* __restrict__ Wd1, const float* __restrict__ Wd2,
                       float* __restrict__ Wd1T, float* __restrict__ Wd2T){
  int t = blockIdx.x*256 + threadIdx.x;
  int stride = gridDim.x*256;
  for (int i = t; i < 85*128; i += stride){
    int j = i >> 7, k = i & 127;
    Wd1T[j*128 + k] = Wd1[k*85 + j];
  }
  for (int i = t; i < 43*85; i += stride){
    int j = i / 85, k = i - j*85;
    Wd2T[j*92 + k] = Wd2[k*43 + j];
  }
}

// ---------------- NextType head, one node per block ----------------
__global__ __launch_bounds__(256) void k_head(
    const float* __restrict__ hl,
    const float* __restrict__ Wl, const float* __restrict__ bl,
    const float* __restrict__ Wd1T, const float* __restrict__ bd1,
    const float* __restrict__ Wd2T, const float* __restrict__ bd2,
    const float* __restrict__ Wd3, const float* __restrict__ bd3,
    const int* __restrict__ batch, float* __restrict__ agg)
{
  __shared__ __align__(16) float hrow[128];
  __shared__ __align__(16) float v[16][132];
  __shared__ __align__(16) float t1s[16][92];
  __shared__ __align__(16) float t2s[16][44];
  __shared__ float t3s[16];
  int tid = threadIdx.x;
  int n = blockIdx.x;

  if (tid < 32) *(f4*)&hrow[tid*4] = *(const f4*)(hl + (size_t)n*H + tid*4);
  __syncthreads();
  {
    int f = tid >> 4, sg = tid & 15;
    int k0 = sg * 8;
    #pragma unroll
    for (int i = 0; i < 8; i++){
      int k = k0 + i;
      v[f][k] = (Wl[f*H + k] + bl[k]) * hrow[k];
    }
  }
  __syncthreads();

  for (int idx = tid; idx < 16*85; idx += 256){
    int f = idx & 15, j = idx >> 4;
    float acc = bd1[j];
    const float* wr = Wd1T + j*128;
    for (int k = 0; k < 128; k += 4){
      f4 a = *(const f4*)&v[f][k];
      f4 w = *(const f4*)&wr[k];
      acc += a[0]*w[0] + a[1]*w[1] + a[2]*w[2] + a[3]*w[3];
    }
    t1s[f][j] = silu_f(acc);
  }
  __syncthreads();

  for (int idx = tid; idx < 16*43; idx += 256){
    int f = idx & 15, j = idx >> 4;
    float acc = bd2[j];
    const float* wr = Wd2T + j*92;
    for (int k = 0; k < 84; k += 4){
      f4 a = *(const f4*)&t1s[f][k];
      f4 w = *(const f4*)&wr[k];
      acc += a[0]*w[0] + a[1]*w[1] + a[2]*w[2] + a[3]*w[3];
    }
    acc += t1s[f][84] * wr[84];
    t2s[f][j] = silu_f(acc);
  }
  __syncthreads();

  if (tid < 16){
    float acc = bd3[0];
    for (int k = 0; k < 43; k++) acc += t2s[tid][k] * Wd3[k];
    t3s[tid] = acc;
  }
  __syncthreads();

  if (tid < 16){
    float m = t3s[0];
    #pragma unroll
    for (int i = 1; i < 16; i++) m = fmaxf(m, t3s[i]);
    float sum = 0.f;
    #pragma unroll
    for (int i = 0; i < 16; i++) sum += __expf(t3s[i] - m);
    float lg = t3s[tid] - m - __logf(sum);
    atomicAdd(&agg[batch[n]*16 + tid], lg);
  }
}

// ---------------- final: out = agg - logsumexp(agg) ----------------
__global__ void k_final(const float* __restrict__ agg, float* __restrict__ out){
  int tid = threadIdx.x; // 128 threads: b = tid>>4, f = tid&15
  float vv = agg[tid];
  float m = vv;
  #pragma unroll
  for (int off = 1; off < 16; off <<= 1) m = fmaxf(m, __shfl_xor(m, off, 64));
  float s = __expf(vv - m);
  #pragma unroll
  for (int off = 1; off < 16; off <<= 1) s += __shfl_xor(s, off, 64);
  out[tid] = vv - m - __logf(s);
}

extern "C" void kernel_launch(void* const* d_in, const int* in_sizes, int n_in,
                              void* d_out, int out_size, void* d_ws, size_t ws_size,
                              hipStream_t stream)
{
  const float* ligand_x   = (const float*)d_in[0];
  const float* pocket_x   = (const float*)d_in[1];
  const float* ligand_pos = (const float*)d_in[2];
  const float* pocket_pos = (const float*)d_in[3];
  const float* Wl_emb = (const float*)d_in[4];
  const float* bl_emb = (const float*)d_in[5];
  const float* Wp_emb = (const float*)d_in[6];
  const float* bp_emb = (const float*)d_in[7];
  const float* We1 = (const float*)d_in[8];
  const float* be1 = (const float*)d_in[9];
  const float* We2 = (const float*)d_in[10];
  const float* be2 = (const float*)d_in[11];
  const float* Wx  = (const float*)d_in[12];
  const float* bx  = (const float*)d_in[13];
  const float* Wh1 = (const float*)d_in[14];
  const float* bh1 = (const float*)d_in[15];
  const float* Wh2 = (const float*)d_in[16];
  const float* bh2 = (const float*)d_in[17];
  const float* Wd1 = (const float*)d_in[18];
  const float* bd1 = (const float*)d_in[19];
  const float* Wd2 = (const float*)d_in[20];
  const float* bd2 = (const float*)d_in[21];
  const float* Wd3 = (const float*)d_in[22];
  const float* bd3 = (const float*)d_in[23];
  const int* l2l    = (const int*)d_in[24];
  const int* p2p    = (const int*)d_in[25];
  const int* lbatch = (const int*)d_in[26];

  char* w = (char*)d_ws;
  auto alloc = [&](size_t bytes)->char*{
    char* p = w; w += (bytes + 255) & ~(size_t)255; return p;
  };
  float* hl    = (float*)alloc((size_t)NLIG*H*4);
  float* hp    = (float*)alloc((size_t)NPOC*H*4);
  float* xl    = (float*)alloc((size_t)NLIG*3*4);
  float* xp    = (float*)alloc((size_t)NPOC*3*4);
  float* agg_m = (float*)alloc((size_t)NPOC*H*4);
  float* agg_x = (float*)alloc((size_t)NPOC*3*4);
  int* deg_l = (int*)alloc((size_t)NLIG*4);
  int* deg_p = (int*)alloc((size_t)NPOC*4);
  int* offs_l = (int*)alloc((size_t)(NLIG+1)*4);
  int* offs_p = (int*)alloc((size_t)(NPOC+1)*4);
  int* cur_l = (int*)alloc((size_t)NLIG*4);
  int* cur_p = (int*)alloc((size_t)NPOC*4);
  int* ssrc_l = (int*)alloc((size_t)ELIG*4);
  int* sdst_l = (int*)alloc((size_t)ELIG*4);
  int* ssrc_p = (int*)alloc((size_t)EPOC*4);
  int* sdst_p = (int*)alloc((size_t)EPOC*4);
  float* Wd1T = (float*)alloc((size_t)85*128*4);
  float* Wd2T = (float*)alloc((size_t)43*92*4);
  float* aggB = (float*)alloc((size_t)NB*16*4);

  hipMemsetAsync(deg_l, 0, (size_t)NLIG*4, stream);
  hipMemsetAsync(deg_p, 0, (size_t)NPOC*4, stream);
  hipMemsetAsync(cur_l, 0, (size_t)NLIG*4, stream);
  hipMemsetAsync(cur_p, 0, (size_t)NPOC*4, stream);
  hipMemsetAsync(aggB, 0, (size_t)NB*16*4, stream);
  hipMemcpyAsync(xl, ligand_pos, (size_t)NLIG*3*4, hipMemcpyDeviceToDevice, stream);
  hipMemcpyAsync(xp, pocket_pos, (size_t)NPOC*3*4, hipMemcpyDeviceToDevice, stream);

  k_embed<<<NLIG/2, 256, 0, stream>>>(ligand_x, Wl_emb, bl_emb, hl, NLIG, FLIG);
  k_embed<<<NPOC/2, 256, 0, stream>>>(pocket_x, Wp_emb, bp_emb, hp, NPOC, FPOC);

  const int* lsrc = l2l;          const int* ldst = l2l + ELIG;
  const int* psrc = p2p;          const int* pdst = p2p + EPOC;

  k_hist<<<(ELIG+255)/256, 256, 0, stream>>>(ldst, deg_l, ELIG);
  k_hist<<<(EPOC+255)/256, 256, 0, stream>>>(pdst, deg_p, EPOC);
  k_scan<<<1, 1024, 0, stream>>>(deg_l, offs_l, NLIG, ELIG);
  k_scan<<<1, 1024, 0, stream>>>(deg_p, offs_p, NPOC, EPOC);
  k_sort<<<(ELIG+255)/256, 256, 0, stream>>>(lsrc, ldst, offs_l, cur_l, ssrc_l, sdst_l, ELIG);
  k_sort<<<(EPOC+255)/256, 256, 0, stream>>>(psrc, pdst, offs_p, cur_p, ssrc_p, sdst_p, EPOC);
  k_prep<<<44, 256, 0, stream>>>(Wd1, Wd2, Wd1T, Wd2T);

  for (int l = 0; l < NLAYERS; l++){
    // ---- ligand (g = 0) ----
    {
      int gl = 0*NLAYERS + l;
      hipMemsetAsync(agg_m, 0, (size_t)NLIG*H*4, stream);
      hipMemsetAsync(agg_x, 0, (size_t)NLIG*3*4, stream);
      k_edge<<<ELIG/32, 256, 0, stream>>>(hl, xl, ssrc_l, sdst_l,
          We1 + (size_t)gl*257*H, be1 + (size_t)gl*H,
          We2 + (size_t)gl*H*H,  be2 + (size_t)gl*H,
          Wx  + (size_t)gl*H,    bx  + gl,
          agg_m, agg_x);
      k_node<<<NLIG/16, 256, 0, stream>>>(hl, xl, agg_m, agg_x, deg_l,
          Wh1 + (size_t)gl*2*H*H, bh1 + (size_t)gl*H,
          Wh2 + (size_t)gl*H*H,   bh2 + (size_t)gl*H);
    }
    // ---- pocket (g = 1) ----
    {
      int gl = 1*NLAYERS + l;
      hipMemsetAsync(agg_m, 0, (size_t)NPOC*H*4, stream);
      hipMemsetAsync(agg_x, 0, (size_t)NPOC*3*4, stream);
      k_edge<<<EPOC/32, 256, 0, stream>>>(hp, xp, ssrc_p, sdst_p,
          We1 + (size_t)gl*257*H, be1 + (size_t)gl*H,
          We2 + (size_t)gl*H*H,  be2 + (size_t)gl*H,
          Wx  + (size_t)gl*H,    bx  + gl,
          agg_m, agg_x);
      k_node<<<NPOC/16, 256, 0, stream>>>(hp, xp, agg_m, agg_x, deg_p,
          Wh1 + (size_t)gl*2*H*H, bh1 + (size_t)gl*H,
          Wh2 + (size_t)gl*H*H,   bh2 + (size_t)gl*H);
    }
  }

  k_head<<<NLIG, 256, 0, stream>>>(hl, Wl_emb, bl_emb, Wd1T, bd1, Wd2T, bd2,
                                   Wd3, bd3, lbatch, aggB);
  k_final<<<1, 128, 0, stream>>>(aggB, (float*)d_out);
}

// Round 2
// 1836.376 us; speedup vs baseline: 1.9001x; 1.9001x over previous
//
#include <hip/hip_runtime.h>
#include <hip/hip_bf16.h>
#include <math.h>

typedef __attribute__((ext_vector_type(4))) float f4;
typedef __attribute__((ext_vector_type(4))) float f32x4;
typedef __attribute__((ext_vector_type(8))) short s8;
typedef __attribute__((ext_vector_type(4))) short s4;

#define H 128
#define NLAYERS 3
#define FLIG 16
#define FPOC 27
#define NLIG 20000
#define NPOC 30000
#define ELIG 160000
#define EPOC 240000
#define NB 8

// packed-weight strides (elements)
#define G1S (8*8*64*8)   // We1 packed per group: 8 ksteps x 8 coltiles x 64 lanes x 8
#define G2S (4*8*64*8)   // We2 packed per group

__device__ __forceinline__ float silu_f(float v){ return v / (1.0f + __expf(-v)); }
__device__ __forceinline__ unsigned short f2bf(float v){
  __hip_bfloat16 b = __float2bfloat16(v);
  return *reinterpret_cast<unsigned short*>(&b);
}

// ---------------- embedding: h = x @ W + b (fp32 + bf16 mirror) ----------------
__global__ void k_embed(const float* __restrict__ x, const float* __restrict__ W,
                        const float* __restrict__ b, float* __restrict__ h,
                        unsigned short* __restrict__ hb, int N, int F){
  int tid = threadIdx.x;
  int n = blockIdx.x*2 + (tid >> 7);
  int j = tid & 127;
  if (n >= N) return;
  float acc = b[j];
  for (int k = 0; k < F; k++) acc += x[n*F + k] * W[k*H + j];
  h[(size_t)n*H + j] = acc;
  hb[(size_t)n*H + j] = f2bf(acc);
}

// ---------------- degree histogram ----------------
__global__ void k_hist(const int* __restrict__ dst, int* __restrict__ deg, int E){
  int e = blockIdx.x*256 + threadIdx.x;
  if (e < E) atomicAdd(&deg[dst[e]], 1);
}

// ---------------- single-block exclusive scan ----------------
__global__ void k_scan(const int* __restrict__ deg, int* __restrict__ offs, int N, int E){
  __shared__ int part[1024];
  int t = threadIdx.x;
  int chunk = (N + 1023) >> 10;
  int b0 = t*chunk;
  int b1 = b0 + chunk; if (b1 > N) b1 = N;
  int s = 0;
  for (int i = b0; i < b1; i++) s += deg[i];
  part[t] = s;
  __syncthreads();
  for (int off = 1; off < 1024; off <<= 1){
    int v = (t >= off) ? part[t-off] : 0;
    __syncthreads();
    part[t] += v;
    __syncthreads();
  }
  int run = part[t] - s;   // exclusive
  for (int i = b0; i < b1; i++){ offs[i] = run; run += deg[i]; }
  if (t == 1023) offs[N] = E;
}

// ---------------- counting-sort scatter ----------------
__global__ void k_sort(const int* __restrict__ src, const int* __restrict__ dst,
                       const int* __restrict__ offs, int* __restrict__ cur,
                       int* __restrict__ ssrc, int* __restrict__ sdst, int E){
  int e = blockIdx.x*256 + threadIdx.x;
  if (e < E){
    int d = dst[e];
    int p = offs[d] + atomicAdd(&cur[d], 1);
    ssrc[p] = src[e];
    sdst[p] = d;
  }
}

// ---------------- weight packer: MFMA fragment order, fp32 -> bf16 ----------------
// We1p[g][ks(8)][t(8)][l(64)][j(8)]  <- We1[g][k=32ks+8*(l>>4)+j][col=16t+(l&15)]
// We2p[g][ks(4)][t(8)][l(64)][j(8)]  <- We2[g][k][col]
__global__ void k_pack(const float* __restrict__ We1, const float* __restrict__ We2,
                       unsigned short* __restrict__ We1p, unsigned short* __restrict__ We2p){
  int idx = blockIdx.x*256 + threadIdx.x;
  const int n1 = 6*G1S;
  const int n2 = 6*G2S;
  if (idx < n1){
    int j = idx & 7, l = (idx>>3)&63, t = (idx>>9)&7, ks = (idx>>12)&7, g = idx>>15;
    int k = 32*ks + 8*(l>>4) + j;
    int col = 16*t + (l&15);
    We1p[idx] = f2bf(We1[((size_t)g*257 + k)*H + col]);
  } else if (idx < n1 + n2){
    int i2 = idx - n1;
    int j = i2 & 7, l = (i2>>3)&63, t = (i2>>9)&7, ks = (i2>>12)&3, g = i2>>14;
    int k = 32*ks + 8*(l>>4) + j;
    int col = 16*t + (l&15);
    We2p[i2] = f2bf(We2[((size_t)g*H + k)*H + col]);
  }
}

// ---------------- fused edge MLP (bf16 MFMA) + scatter ----------------
// 64 edges/block, 4 waves; wave w owns edges [w*16, w*16+16), all 128 cols.
__global__ __launch_bounds__(256, 3) void k_edge_mfma(
    const unsigned short* __restrict__ hb, const float* __restrict__ x,
    const int* __restrict__ ssrc, const int* __restrict__ sdst,
    const unsigned short* __restrict__ We1p, const float* __restrict__ We1r256,
    const float* __restrict__ be1,
    const unsigned short* __restrict__ We2p, const float* __restrict__ be2,
    const float* __restrict__ Wx, const float* __restrict__ bxp,
    float* __restrict__ agg_m, float* __restrict__ agg_x)
{
  __shared__ __align__(16) unsigned short m_lds[128*68]; // m bf16, col-major [k2][edge], stride 68
  __shared__ __align__(16) float m2_lds[64][132];        // m2 fp32, row-major [edge][j2]
  __shared__ float relS[64][3];
  __shared__ float d2S[64];
  __shared__ int sI[64], dI[64];

  int tid = threadIdx.x;
  int e0 = blockIdx.x * 64;

  if (tid < 64){
    int s = ssrc[e0+tid], d = sdst[e0+tid];
    sI[tid] = s; dI[tid] = d;
    float rx = x[d*3+0]-x[s*3+0];
    float ry = x[d*3+1]-x[s*3+1];
    float rz = x[d*3+2]-x[s*3+2];
    relS[tid][0]=rx; relS[tid][1]=ry; relS[tid][2]=rz;
    d2S[tid] = rx*rx+ry*ry+rz*rz;
  }
  __syncthreads();

  int lane = tid & 63, wave = tid >> 6;
  int c = lane & 15, q = lane >> 4;
  int eA = wave*16 + c;                 // this lane's A-row edge (local)
  size_t rowD = (size_t)dI[eA]*H, rowS = (size_t)sI[eA]*H;
  const unsigned short* pD = hb + rowD + q*8;
  const unsigned short* pS = hb + rowS + q*8;

  // ---- GEMM1: e_in[64x256] @ We1[256x128] via MFMA (d2 row handled fp32) ----
  f32x4 acc[8];
  #pragma unroll
  for (int t=0;t<8;t++) acc[t] = (f32x4){0.f,0.f,0.f,0.f};

  // prefetch all 8 A-fragments (this lane's k-slices of h[dst] / h[src])
  s8 afr[8];
  #pragma unroll
  for (int ks=0; ks<8; ks++)
    afr[ks] = *(const s8*)((ks<4) ? (pD + ks*32) : (pS + (ks-4)*32));

  const s8* B1 = (const s8*)We1p;
  #pragma unroll
  for (int ks=0; ks<8; ks++){
    const s8* bp = B1 + (ks*8)*64 + lane;
    #pragma unroll
    for (int t=0;t<8;t++)
      acc[t] = __builtin_amdgcn_mfma_f32_16x16x32_bf16(afr[ks], bp[t*64], acc[t], 0,0,0);
  }

  // d2 (row 256, fp32) + bias + silu; write m to LDS col-major bf16
  int er0 = wave*16 + 4*q;              // first of this lane's 4 C-rows (edges)
  float d2v[4];
  #pragma unroll
  for (int i=0;i<4;i++) d2v[i] = d2S[er0+i];
  #pragma unroll
  for (int t=0;t<8;t++){
    int j2 = 16*t + c;
    float w256 = We1r256[j2], bias = be1[j2];
    s4 mv;
    #pragma unroll
    for (int i=0;i<4;i++){
      float v = silu_f(acc[t][i] + d2v[i]*w256 + bias);
      mv[i] = (short)f2bf(v);
    }
    *(s4*)&m_lds[68*j2 + er0] = mv;     // 4 consecutive edges, one b64 write
  }
  __syncthreads();

  // ---- GEMM2: m[64x128] @ We2[128x128] via MFMA ----
  f32x4 acc2[8];
  #pragma unroll
  for (int t=0;t<8;t++) acc2[t] = (f32x4){0.f,0.f,0.f,0.f};

  const s8* B2 = (const s8*)We2p;
  #pragma unroll
  for (int ks=0; ks<4; ks++){
    s8 a2;
    int base = 68*(32*ks + 8*q) + wave*16 + c;
    #pragma unroll
    for (int j=0;j<8;j++) a2[j] = (short)m_lds[base + 68*j];
    const s8* bp = B2 + (ks*8)*64 + lane;
    #pragma unroll
    for (int t=0;t<8;t++)
      acc2[t] = __builtin_amdgcn_mfma_f32_16x16x32_bf16(a2, bp[t*64], acc2[t], 0,0,0);
  }

  // silu + coef partials + stash m2 (fp32) row-major
  float pp[4] = {0.f,0.f,0.f,0.f};
  #pragma unroll
  for (int t=0;t<8;t++){
    int j2 = 16*t + c;
    float b2 = be2[j2], wx = Wx[j2];
    #pragma unroll
    for (int i=0;i<4;i++){
      float v = silu_f(acc2[t][i] + b2);
      m2_lds[er0+i][j2] = v;
      pp[i] += v * wx;
    }
  }
  // reduce coef over the 16 j-lanes (c), q preserved
  #pragma unroll
  for (int off=1; off<16; off<<=1){
    #pragma unroll
    for (int i=0;i<4;i++) pp[i] += __shfl_xor(pp[i], off, 64);
  }
  if (c == 0){
    float bxv = bxp[0];
    #pragma unroll
    for (int i=0;i<4;i++){
      int e = er0 + i;
      float cf = pp[i] + bxv;
      int d = dI[e];
      atomicAdd(&agg_x[(size_t)d*3+0], relS[e][0]*cf);
      atomicAdd(&agg_x[(size_t)d*3+1], relS[e][1]*cf);
      atomicAdd(&agg_x[(size_t)d*3+2], relS[e][2]*cf);
    }
  }
  __syncthreads();

  // segmented scatter of m2 into agg_m (edges sorted by dst)
  {
    int j = tid & 127, half = tid >> 7;
    int eb = half*32;
    float sacc = 0.f; int run = dI[eb];
    for (int e = eb; e < eb+32; e++){
      int d = dI[e];
      if (d != run){ atomicAdd(&agg_m[(size_t)run*H + j], sacc); sacc = 0.f; run = d; }
      sacc += m2_lds[e][j];
    }
    atomicAdd(&agg_m[(size_t)run*H + j], sacc);
  }
}

// ---------------- fused node update (fp32 VALU) + bf16 mirror write ----------------
__global__ __launch_bounds__(256) void k_node(
    float* __restrict__ h, unsigned short* __restrict__ hbm, float* __restrict__ x,
    const float* __restrict__ agg_m, const float* __restrict__ agg_x,
    const int* __restrict__ degi,
    const float* __restrict__ Wh1, const float* __restrict__ bh1,
    const float* __restrict__ Wh2, const float* __restrict__ bh2)
{
  __shared__ __align__(16) float hc[16][260];  // [h | agg_m]
  __shared__ __align__(16) float u1[16][132];
  int tid = threadIdx.x;
  int n0b = blockIdx.x * 16;

  if (tid < 48){
    int nn = tid / 3, cc = tid - nn*3;
    int gn = n0b + nn;
    float dv = (float)degi[gn]; if (dv < 1.f) dv = 1.f;
    x[(size_t)gn*3 + cc] += agg_x[(size_t)gn*3 + cc] / dv;
  }
  {
    int ge = tid >> 4, gp = tid & 15;
    int gn = n0b + ge;
    const float* sp = (gp < 8) ? (h + (size_t)gn*H + gp*16)
                               : (agg_m + (size_t)gn*H + (gp-8)*16);
    f4* d4 = (f4*)&hc[ge][gp*16];
    const f4* s4v = (const f4*)sp;
    #pragma unroll
    for (int i = 0; i < 4; i++) d4[i] = s4v[i];
  }
  __syncthreads();

  int jg = tid & 31, ng = tid >> 5;
  int j0 = jg*4, n0 = ng*2;

  float acc[2][4];
  #pragma unroll
  for (int i = 0; i < 2; i++)
    #pragma unroll
    for (int jj = 0; jj < 4; jj++) acc[i][jj] = 0.f;

  for (int k = 0; k < 256; k += 4){
    f4 A0 = *(const f4*)&hc[n0+0][k];
    f4 A1 = *(const f4*)&hc[n0+1][k];
    f4 B0 = *(const f4*)(Wh1 + (size_t)(k+0)*H + j0);
    f4 B1 = *(const f4*)(Wh1 + (size_t)(k+1)*H + j0);
    f4 B2 = *(const f4*)(Wh1 + (size_t)(k+2)*H + j0);
    f4 B3 = *(const f4*)(Wh1 + (size_t)(k+3)*H + j0);
    #pragma unroll
    for (int jj = 0; jj < 4; jj++){
      acc[0][jj] += A0[0]*B0[jj] + A0[1]*B1[jj] + A0[2]*B2[jj] + A0[3]*B3[jj];
      acc[1][jj] += A1[0]*B0[jj] + A1[1]*B1[jj] + A1[2]*B2[jj] + A1[3]*B3[jj];
    }
  }
  {
    f4 b1 = *(const f4*)(bh1 + j0);
    #pragma unroll
    for (int i = 0; i < 2; i++){
      f4 u;
      #pragma unroll
      for (int jj = 0; jj < 4; jj++) u[jj] = silu_f(acc[i][jj] + b1[jj]);
      *(f4*)&u1[n0+i][j0] = u;
    }
  }
  __syncthreads();

  float acc2[2][4];
  #pragma unroll
  for (int i = 0; i < 2; i++)
    #pragma unroll
    for (int jj = 0; jj < 4; jj++) acc2[i][jj] = 0.f;

  for (int k = 0; k < 128; k += 4){
    f4 A0 = *(const f4*)&u1[n0+0][k];
    f4 A1 = *(const f4*)&u1[n0+1][k];
    f4 B0 = *(const f4*)(Wh2 + (size_t)(k+0)*H + j0);
    f4 B1 = *(const f4*)(Wh2 + (size_t)(k+1)*H + j0);
    f4 B2 = *(const f4*)(Wh2 + (size_t)(k+2)*H + j0);
    f4 B3 = *(const f4*)(Wh2 + (size_t)(k+3)*H + j0);
    #pragma unroll
    for (int jj = 0; jj < 4; jj++){
      acc2[0][jj] += A0[0]*B0[jj] + A0[1]*B1[jj] + A0[2]*B2[jj] + A0[3]*B3[jj];
      acc2[1][jj] += A1[0]*B0[jj] + A1[1]*B1[jj] + A1[2]*B2[jj] + A1[3]*B3[jj];
    }
  }
  {
    f4 b2 = *(const f4*)(bh2 + j0);
    #pragma unroll
    for (int i = 0; i < 2; i++){
      f4 hv;
      #pragma unroll
      for (int jj = 0; jj < 4; jj++) hv[jj] = hc[n0+i][j0+jj] + acc2[i][jj] + b2[jj];
      size_t off = (size_t)(n0b+n0+i)*H + j0;
      *(f4*)(h + off) = hv;
      s4 hv16;
      #pragma unroll
      for (int jj = 0; jj < 4; jj++) hv16[jj] = (short)f2bf(hv[jj]);
      *(s4*)(hbm + off) = hv16;
    }
  }
}

// ---------------- NextType head v2: 4 nodes/block, conflict-free fp32 ----------------
__global__ __launch_bounds__(256, 2) void k_head2(
    const float* __restrict__ hl,
    const float* __restrict__ Wl, const float* __restrict__ bl,
    const float* __restrict__ Wd1, const float* __restrict__ bd1,
    const float* __restrict__ Wd2, const float* __restrict__ bd2,
    const float* __restrict__ Wd3, const float* __restrict__ bd3,
    const int* __restrict__ batch, float* __restrict__ agg)
{
  __shared__ __align__(16) float bufU[8448];       // v2[64][132]  OR  Wd2s+ t2s + t3s
  __shared__ __align__(16) float t1s[64][88];
  float* v2   = bufU;                // [r][k] stride 132
  float* Wd2s = bufU;                // [85][44]
  float* t2s  = bufU + 85*44;        // [64][44]
  float* t3s  = bufU + 85*44 + 64*44;// [64]
  int tid = threadIdx.x;
  int nb0 = blockIdx.x * 4;

  // Phase A: v2[r=n*16+f][k] = (Wl[f][k]+bl[k]) * hl[nb0+n][k]
  {
    int r = tid >> 2, kb = (tid & 3) * 32;
    int f = r & 15, n = r >> 4;
    const float* hrow = hl + (size_t)(nb0+n)*H;
    for (int k = kb; k < kb+32; k += 4){
      f4 wv = *(const f4*)&Wl[f*H + k];
      f4 bv = *(const f4*)&bl[k];
      f4 hv = *(const f4*)&hrow[k];
      f4 ov;
      #pragma unroll
      for (int jj=0;jj<4;jj++) ov[jj] = (wv[jj]+bv[jj])*hv[jj];
      *(f4*)&v2[r*132 + k] = ov;
    }
  }
  __syncthreads();

  // Phase B: t1 = silu(v2 @ Wd1 + bd1)   (thread: 8 rows x 3 cols)
  {
    int rg = tid >> 5, jg = tid & 31;
    int r0 = rg*8, jb = jg*3;
    bool v0 = jb < 85, v1 = jb+1 < 85, v2m = jb+2 < 85;
    int j0i = v0 ? jb : 0, j1i = v1 ? jb+1 : 0, j2i = v2m ? jb+2 : 0;
    float accr[8][3];
    #pragma unroll
    for (int rr=0;rr<8;rr++){ accr[rr][0]=0.f; accr[rr][1]=0.f; accr[rr][2]=0.f; }
    for (int k = 0; k < 128; k++){
      float w0 = Wd1[k*85 + j0i], w1 = Wd1[k*85 + j1i], w2 = Wd1[k*85 + j2i];
      #pragma unroll
      for (int rr=0; rr<8; rr++){
        float a = v2[(r0+rr)*132 + k];
        accr[rr][0] += a*w0; accr[rr][1] += a*w1; accr[rr][2] += a*w2;
      }
    }
    if (v0){ float b = bd1[jb];
      #pragma unroll
      for (int rr=0;rr<8;rr++) t1s[r0+rr][jb]   = silu_f(accr[rr][0]+b); }
    if (v1){ float b = bd1[jb+1];
      #pragma unroll
      for (int rr=0;rr<8;rr++) t1s[r0+rr][jb+1] = silu_f(accr[rr][1]+b); }
    if (v2m){ float b = bd1[jb+2];
      #pragma unroll
      for (int rr=0;rr<8;rr++) t1s[r0+rr][jb+2] = silu_f(accr[rr][2]+b); }
  }
  __syncthreads();
  // overlay load Wd2 (v2 now dead)
  for (int idx = tid; idx < 85*43; idx += 256){
    int k = idx / 43, j = idx - k*43;
    Wd2s[k*44 + j] = Wd2[idx];
  }
  __syncthreads();

  // Phase C: t2 = silu(t1 @ Wd2 + bd2)   (thread: 8 rows x 2 cols)
  {
    int rg = tid >> 5, jg = tid & 31;
    int r0 = rg*8, jb = jg*2;
    bool v0 = jb < 43, v1 = jb+1 < 43;
    int j0i = v0 ? jb : 0, j1i = v1 ? jb+1 : 0;
    float accr[8][2];
    #pragma unroll
    for (int rr=0;rr<8;rr++){ accr[rr][0]=0.f; accr[rr][1]=0.f; }
    for (int k = 0; k < 85; k++){
      float w0 = Wd2s[k*44 + j0i], w1 = Wd2s[k*44 + j1i];
      #pragma unroll
      for (int rr=0; rr<8; rr++){
        float a = t1s[r0+rr][k];
        accr[rr][0] += a*w0; accr[rr][1] += a*w1;
      }
    }
    if (v0){ float b = bd2[jb];
      #pragma unroll
      for (int rr=0;rr<8;rr++) t2s[(r0+rr)*44 + jb]   = silu_f(accr[rr][0]+b); }
    if (v1){ float b = bd2[jb+1];
      #pragma unroll
      for (int rr=0;rr<8;rr++) t2s[(r0+rr)*44 + jb+1] = silu_f(accr[rr][1]+b); }
  }
  __syncthreads();

  // Phase D: t3[r] = t2[r] @ Wd3 + bd3
  if (tid < 64){
    float acc = bd3[0];
    for (int k = 0; k < 43; k++) acc += t2s[tid*44 + k] * Wd3[k];
    t3s[tid] = acc;
  }
  __syncthreads();

  // Phase E: per-node log-softmax over 16 types + batch scatter
  if (tid < 64){
    int n = tid >> 4, f = tid & 15;
    const float* tb = t3s + n*16;
    float m = tb[0];
    #pragma unroll
    for (int i = 1; i < 16; i++) m = fmaxf(m, tb[i]);
    float s = 0.f;
    #pragma unroll
    for (int i = 0; i < 16; i++) s += __expf(tb[i] - m);
    float lg = t3s[tid] - m - __logf(s);
    atomicAdd(&agg[batch[nb0+n]*16 + f], lg);
  }
}

// ---------------- final: out = agg - logsumexp(agg) ----------------
__global__ void k_final(const float* __restrict__ agg, float* __restrict__ out){
  int tid = threadIdx.x; // 128 threads: b = tid>>4, f = tid&15
  float vv = agg[tid];
  float m = vv;
  #pragma unroll
  for (int off = 1; off < 16; off <<= 1) m = fmaxf(m, __shfl_xor(m, off, 64));
  float s = __expf(vv - m);
  #pragma unroll
  for (int off = 1; off < 16; off <<= 1) s += __shfl_xor(s, off, 64);
  out[tid] = vv - m - __logf(s);
}

extern "C" void kernel_launch(void* const* d_in, const int* in_sizes, int n_in,
                              void* d_out, int out_size, void* d_ws, size_t ws_size,
                              hipStream_t stream)
{
  const float* ligand_x   = (const float*)d_in[0];
  const float* pocket_x   = (const float*)d_in[1];
  const float* ligand_pos = (const float*)d_in[2];
  const float* pocket_pos = (const float*)d_in[3];
  const float* Wl_emb = (const float*)d_in[4];
  const float* bl_emb = (const float*)d_in[5];
  const float* Wp_emb = (const float*)d_in[6];
  const float* bp_emb = (const float*)d_in[7];
  const float* We1 = (const float*)d_in[8];
  const float* be1 = (const float*)d_in[9];
  const float* We2 = (const float*)d_in[10];
  const float* be2 = (const float*)d_in[11];
  const float* Wx  = (const float*)d_in[12];
  const float* bx  = (const float*)d_in[13];
  const float* Wh1 = (const float*)d_in[14];
  const float* bh1 = (const float*)d_in[15];
  const float* Wh2 = (const float*)d_in[16];
  const float* bh2 = (const float*)d_in[17];
  const float* Wd1 = (const float*)d_in[18];
  const float* bd1 = (const float*)d_in[19];
  const float* Wd2 = (const float*)d_in[20];
  const float* bd2 = (const float*)d_in[21];
  const float* Wd3 = (const float*)d_in[22];
  const float* bd3 = (const float*)d_in[23];
  const int* l2l    = (const int*)d_in[24];
  const int* p2p    = (const int*)d_in[25];
  const int* lbatch = (const int*)d_in[26];

  char* w = (char*)d_ws;
  auto alloc = [&](size_t bytes)->char*{
    char* p = w; w += (bytes + 255) & ~(size_t)255; return p;
  };
  float* hl    = (float*)alloc((size_t)NLIG*H*4);
  float* hp    = (float*)alloc((size_t)NPOC*H*4);
  unsigned short* hbl = (unsigned short*)alloc((size_t)NLIG*H*2);
  unsigned short* hbp = (unsigned short*)alloc((size_t)NPOC*H*2);
  float* xl    = (float*)alloc((size_t)NLIG*3*4);
  float* xp    = (float*)alloc((size_t)NPOC*3*4);
  float* agg_m = (float*)alloc((size_t)NPOC*H*4);
  float* agg_x = (float*)alloc((size_t)NPOC*3*4);
  int* deg_l = (int*)alloc((size_t)NLIG*4);
  int* deg_p = (int*)alloc((size_t)NPOC*4);
  int* offs_l = (int*)alloc((size_t)(NLIG+1)*4);
  int* offs_p = (int*)alloc((size_t)(NPOC+1)*4);
  int* cur_l = (int*)alloc((size_t)NLIG*4);
  int* cur_p = (int*)alloc((size_t)NPOC*4);
  int* ssrc_l = (int*)alloc((size_t)ELIG*4);
  int* sdst_l = (int*)alloc((size_t)ELIG*4);
  int* ssrc_p = (int*)alloc((size_t)EPOC*4);
  int* sdst_p = (int*)alloc((size_t)EPOC*4);
  unsigned short* We1p = (unsigned short*)alloc((size_t)6*G1S*2);
  unsigned short* We2p = (unsigned short*)alloc((size_t)6*G2S*2);
  float* aggB = (float*)alloc((size_t)NB*16*4);

  hipMemsetAsync(deg_l, 0, (size_t)NLIG*4, stream);
  hipMemsetAsync(deg_p, 0, (size_t)NPOC*4, stream);
  hipMemsetAsync(cur_l, 0, (size_t)NLIG*4, stream);
  hipMemsetAsync(cur_p, 0, (size_t)NPOC*4, stream);
  hipMemsetAsync(aggB, 0, (size_t)NB*16*4, stream);
  hipMemcpyAsync(xl, ligand_pos, (size_t)NLIG*3*4, hipMemcpyDeviceToDevice, stream);
  hipMemcpyAsync(xp, pocket_pos, (size_t)NPOC*3*4, hipMemcpyDeviceToDevice, stream);

  k_embed<<<NLIG/2, 256, 0, stream>>>(ligand_x, Wl_emb, bl_emb, hl, hbl, NLIG, FLIG);
  k_embed<<<NPOC/2, 256, 0, stream>>>(pocket_x, Wp_emb, bp_emb, hp, hbp, NPOC, FPOC);

  const int* lsrc = l2l;          const int* ldst = l2l + ELIG;
  const int* psrc = p2p;          const int* pdst = p2p + EPOC;

  k_hist<<<(ELIG+255)/256, 256, 0, stream>>>(ldst, deg_l, ELIG);
  k_hist<<<(EPOC+255)/256, 256, 0, stream>>>(pdst, deg_p, EPOC);
  k_scan<<<1, 1024, 0, stream>>>(deg_l, offs_l, NLIG, ELIG);
  k_scan<<<1, 1024, 0, stream>>>(deg_p, offs_p, NPOC, EPOC);
  k_sort<<<(ELIG+255)/256, 256, 0, stream>>>(lsrc, ldst, offs_l, cur_l, ssrc_l, sdst_l, ELIG);
  k_sort<<<(EPOC+255)/256, 256, 0, stream>>>(psrc, pdst, offs_p, cur_p, ssrc_p, sdst_p, EPOC);
  k_pack<<<(6*G1S + 6*G2S + 255)/256, 256, 0, stream>>>(We1, We2, We1p, We2p);

  for (int l = 0; l < NLAYERS; l++){
    // ---- ligand (g = 0) ----
    {
      int gl = 0*NLAYERS + l;
      hipMemsetAsync(agg_m, 0, (size_t)NLIG*H*4, stream);
      hipMemsetAsync(agg_x, 0, (size_t)NLIG*3*4, stream);
      k_edge_mfma<<<ELIG/64, 256, 0, stream>>>(hbl, xl, ssrc_l, sdst_l,
          We1p + (size_t)gl*G1S, We1 + (size_t)gl*257*H + 256*H, be1 + (size_t)gl*H,
          We2p + (size_t)gl*G2S, be2 + (size_t)gl*H,
          Wx  + (size_t)gl*H,    bx  + gl,
          agg_m, agg_x);
      k_node<<<NLIG/16, 256, 0, stream>>>(hl, hbl, xl, agg_m, agg_x, deg_l,
          Wh1 + (size_t)gl*2*H*H, bh1 + (size_t)gl*H,
          Wh2 + (size_t)gl*H*H,   bh2 + (size_t)gl*H);
    }
    // ---- pocket (g = 1) ----
    {
      int gl = 1*NLAYERS + l;
      hipMemsetAsync(agg_m, 0, (size_t)NPOC*H*4, stream);
      hipMemsetAsync(agg_x, 0, (size_t)NPOC*3*4, stream);
      k_edge_mfma<<<EPOC/64, 256, 0, stream>>>(hbp, xp, ssrc_p, sdst_p,
          We1p + (size_t)gl*G1S, We1 + (size_t)gl*257*H + 256*H, be1 + (size_t)gl*H,
          We2p + (size_t)gl*G2S, be2 + (size_t)gl*H,
          Wx  + (size_t)gl*H,    bx  + gl,
          agg_m, agg_x);
      k_node<<<NPOC/16, 256, 0, stream>>>(hp, hbp, xp, agg_m, agg_x, deg_p,
          Wh1 + (size_t)gl*2*H*H, bh1 + (size_t)gl*H,
          Wh2 + (size_t)gl*H*H,   bh2 + (size_t)gl*H);
    }
  }

  k_head2<<<NLIG/4, 256, 0, stream>>>(hl, Wl_emb, bl_emb, Wd1, bd1, Wd2, bd2,
                                      Wd3, bd3, lbatch, aggB);
  k_final<<<1, 128, 0, stream>>>(aggB, (float*)d_out);
}

// Round 3
// 1026.636 us; speedup vs baseline: 3.3987x; 1.7887x over previous
//
#include <hip/hip_runtime.h>
#include <hip/hip_bf16.h>
#include <math.h>

typedef __attribute__((ext_vector_type(4))) float f4;
typedef __attribute__((ext_vector_type(4))) float f32x4;
typedef __attribute__((ext_vector_type(8))) short s8;
typedef __attribute__((ext_vector_type(4))) short s4;

#define H 128
#define NLAYERS 3
#define FLIG 16
#define FPOC 27
#define NLIG 20000
#define NPOC 30000
#define ELIG 160000
#define EPOC 240000
#define NB 8

// packed-weight strides (elements)
#define G1S (8*8*64*8)   // K=256-ish GEMM1 weights per group (8 ksteps x 8 coltiles)
#define G2S (4*8*64*8)   // K=128 GEMM2 weights per group
#define W1FS (4*6*64*8)  // head W1f per f: 4 ksteps x 6 coltiles
#define WD2S (3*3*64*8)  // head Wd2: 3 ksteps x 3 coltiles

__device__ __forceinline__ float silu_f(float v){ return v / (1.0f + __expf(-v)); }
__device__ __forceinline__ unsigned short f2bf(float v){
  __hip_bfloat16 b = __float2bfloat16(v);
  return *reinterpret_cast<unsigned short*>(&b);
}

// ---------------- embedding: h = x @ W + b (fp32 + bf16 mirror) ----------------
__global__ void k_embed(const float* __restrict__ x, const float* __restrict__ W,
                        const float* __restrict__ b, float* __restrict__ h,
                        unsigned short* __restrict__ hb, int N, int F){
  int tid = threadIdx.x;
  int n = blockIdx.x*2 + (tid >> 7);
  int j = tid & 127;
  if (n >= N) return;
  float acc = b[j];
  for (int k = 0; k < F; k++) acc += x[n*F + k] * W[k*H + j];
  h[(size_t)n*H + j] = acc;
  hb[(size_t)n*H + j] = f2bf(acc);
}

// ---------------- degree histogram ----------------
__global__ void k_hist(const int* __restrict__ dst, int* __restrict__ deg, int E){
  int e = blockIdx.x*256 + threadIdx.x;
  if (e < E) atomicAdd(&deg[dst[e]], 1);
}

// ---------------- single-block exclusive scan ----------------
__global__ void k_scan(const int* __restrict__ deg, int* __restrict__ offs, int N, int E){
  __shared__ int part[1024];
  int t = threadIdx.x;
  int chunk = (N + 1023) >> 10;
  int b0 = t*chunk;
  int b1 = b0 + chunk; if (b1 > N) b1 = N;
  int s = 0;
  for (int i = b0; i < b1; i++) s += deg[i];
  part[t] = s;
  __syncthreads();
  for (int off = 1; off < 1024; off <<= 1){
    int v = (t >= off) ? part[t-off] : 0;
    __syncthreads();
    part[t] += v;
    __syncthreads();
  }
  int run = part[t] - s;   // exclusive
  for (int i = b0; i < b1; i++){ offs[i] = run; run += deg[i]; }
  if (t == 1023) offs[N] = E;
}

// ---------------- counting-sort scatter ----------------
__global__ void k_sort(const int* __restrict__ src, const int* __restrict__ dst,
                       const int* __restrict__ offs, int* __restrict__ cur,
                       int* __restrict__ ssrc, int* __restrict__ sdst, int E){
  int e = blockIdx.x*256 + threadIdx.x;
  if (e < E){
    int d = dst[e];
    int p = offs[d] + atomicAdd(&cur[d], 1);
    ssrc[p] = src[e];
    sdst[p] = d;
  }
}

// ---------------- weight packer: MFMA fragment order, fp32 -> bf16 ----------------
__global__ void k_pack(const float* __restrict__ We1, const float* __restrict__ We2,
                       const float* __restrict__ Wh1, const float* __restrict__ Wh2,
                       const float* __restrict__ Wl, const float* __restrict__ bl,
                       const float* __restrict__ Wd1, const float* __restrict__ Wd2,
                       unsigned short* __restrict__ We1p, unsigned short* __restrict__ We2p,
                       unsigned short* __restrict__ Wh1p, unsigned short* __restrict__ Wh2p,
                       unsigned short* __restrict__ W1p, unsigned short* __restrict__ Wd2p)
{
  int idx = blockIdx.x*256 + threadIdx.x;
  const int nWe1 = 6*G1S, nWe2 = 6*G2S, nWh1 = 6*G1S, nWh2 = 6*G2S, nW1 = 16*W1FS, nWd2 = WD2S;
  int i = idx;
  if (i < nWe1){
    int j = i&7, l = (i>>3)&63, t = (i>>9)&7, ks = (i>>12)&7, g = i>>15;
    int k = 32*ks + 8*(l>>4) + j, col = 16*t + (l&15);
    We1p[i] = f2bf(We1[((size_t)g*257 + k)*H + col]);
    return;
  }
  i -= nWe1;
  if (i < nWe2){
    int j = i&7, l = (i>>3)&63, t = (i>>9)&7, ks = (i>>12)&3, g = i>>14;
    int k = 32*ks + 8*(l>>4) + j, col = 16*t + (l&15);
    We2p[i] = f2bf(We2[((size_t)g*H + k)*H + col]);
    return;
  }
  i -= nWe2;
  if (i < nWh1){
    int j = i&7, l = (i>>3)&63, t = (i>>9)&7, ks = (i>>12)&7, g = i>>15;
    int k = 32*ks + 8*(l>>4) + j, col = 16*t + (l&15);
    Wh1p[i] = f2bf(Wh1[((size_t)g*256 + k)*H + col]);
    return;
  }
  i -= nWh1;
  if (i < nWh2){
    int j = i&7, l = (i>>3)&63, t = (i>>9)&7, ks = (i>>12)&3, g = i>>14;
    int k = 32*ks + 8*(l>>4) + j, col = 16*t + (l&15);
    Wh2p[i] = f2bf(Wh2[((size_t)g*H + k)*H + col]);
    return;
  }
  i -= nWh2;
  if (i < nW1){
    int f = i / W1FS, r = i % W1FS;
    int ks = r / (6*512), r2 = r % (6*512);
    int t = r2 / 512, l = (r2 % 512) >> 3, j = r2 & 7;
    int k = 32*ks + 8*(l>>4) + j, col = 16*t + (l&15);
    float v = 0.f;
    if (col < 85) v = (Wl[f*H + k] + bl[k]) * Wd1[k*85 + col];
    W1p[i] = f2bf(v);
    return;
  }
  i -= nW1;
  if (i < nWd2){
    int ks = i / (3*512), r2 = i % (3*512);
    int t = r2 / 512, l = (r2 % 512) >> 3, j = r2 & 7;
    int k = 32*ks + 8*(l>>4) + j, col = 16*t + (l&15);
    float v = 0.f;
    if (k < 85 && col < 43) v = Wd2[k*43 + col];
    Wd2p[i] = f2bf(v);
  }
}

// ---------------- fused edge MLP (bf16 MFMA) + scatter ----------------
__global__ __launch_bounds__(256, 3) void k_edge_mfma(
    const unsigned short* __restrict__ hb, const float* __restrict__ x,
    const int* __restrict__ ssrc, const int* __restrict__ sdst,
    const unsigned short* __restrict__ We1p, const float* __restrict__ We1r256,
    const float* __restrict__ be1,
    const unsigned short* __restrict__ We2p, const float* __restrict__ be2,
    const float* __restrict__ Wx, const float* __restrict__ bxp,
    float* __restrict__ agg_m, float* __restrict__ agg_x)
{
  __shared__ __align__(16) unsigned short m_lds[128*70]; // m bf16, col-major [k2][edge], stride 70
  __shared__ __align__(16) float m2_lds[64][132];        // m2 fp32, row-major [edge][j2]
  __shared__ float relS[64][3];
  __shared__ float d2S[64];
  __shared__ int sI[64], dI[64];

  int tid = threadIdx.x;
  int e0 = blockIdx.x * 64;

  if (tid < 64){
    int s = ssrc[e0+tid], d = sdst[e0+tid];
    sI[tid] = s; dI[tid] = d;
    float rx = x[d*3+0]-x[s*3+0];
    float ry = x[d*3+1]-x[s*3+1];
    float rz = x[d*3+2]-x[s*3+2];
    relS[tid][0]=rx; relS[tid][1]=ry; relS[tid][2]=rz;
    d2S[tid] = rx*rx+ry*ry+rz*rz;
  }
  __syncthreads();

  int lane = tid & 63, wave = tid >> 6;
  int c = lane & 15, q = lane >> 4;
  int eA = wave*16 + c;
  size_t rowD = (size_t)dI[eA]*H, rowS = (size_t)sI[eA]*H;
  const unsigned short* pD = hb + rowD + q*8;
  const unsigned short* pS = hb + rowS + q*8;

  f32x4 acc[8];
  #pragma unroll
  for (int t=0;t<8;t++) acc[t] = (f32x4){0.f,0.f,0.f,0.f};

  s8 afr[8];
  #pragma unroll
  for (int ks=0; ks<8; ks++)
    afr[ks] = *(const s8*)((ks<4) ? (pD + ks*32) : (pS + (ks-4)*32));

  const s8* B1 = (const s8*)We1p;
  #pragma unroll
  for (int ks=0; ks<8; ks++){
    const s8* bp = B1 + (ks*8)*64 + lane;
    #pragma unroll
    for (int t=0;t<8;t++)
      acc[t] = __builtin_amdgcn_mfma_f32_16x16x32_bf16(afr[ks], bp[t*64], acc[t], 0,0,0);
  }

  int er0 = wave*16 + 4*q;
  float d2v[4];
  #pragma unroll
  for (int i=0;i<4;i++) d2v[i] = d2S[er0+i];
  #pragma unroll
  for (int t=0;t<8;t++){
    int j2 = 16*t + c;
    float w256 = We1r256[j2], bias = be1[j2];
    s4 mv;
    #pragma unroll
    for (int i=0;i<4;i++){
      float v = silu_f(acc[t][i] + d2v[i]*w256 + bias);
      mv[i] = (short)f2bf(v);
    }
    *(s4*)&m_lds[70*j2 + er0] = mv;
  }
  __syncthreads();

  f32x4 acc2[8];
  #pragma unroll
  for (int t=0;t<8;t++) acc2[t] = (f32x4){0.f,0.f,0.f,0.f};

  const s8* B2 = (const s8*)We2p;
  #pragma unroll
  for (int ks=0; ks<4; ks++){
    s8 a2;
    int base = 70*(32*ks + 8*q) + wave*16 + c;
    #pragma unroll
    for (int j=0;j<8;j++) a2[j] = (short)m_lds[base + 70*j];
    const s8* bp = B2 + (ks*8)*64 + lane;
    #pragma unroll
    for (int t=0;t<8;t++)
      acc2[t] = __builtin_amdgcn_mfma_f32_16x16x32_bf16(a2, bp[t*64], acc2[t], 0,0,0);
  }

  float pp[4] = {0.f,0.f,0.f,0.f};
  #pragma unroll
  for (int t=0;t<8;t++){
    int j2 = 16*t + c;
    float b2 = be2[j2], wx = Wx[j2];
    #pragma unroll
    for (int i=0;i<4;i++){
      float v = silu_f(acc2[t][i] + b2);
      m2_lds[er0+i][j2] = v;
      pp[i] += v * wx;
    }
  }
  #pragma unroll
  for (int off=1; off<16; off<<=1){
    #pragma unroll
    for (int i=0;i<4;i++) pp[i] += __shfl_xor(pp[i], off, 64);
  }
  if (c == 0){
    float bxv = bxp[0];
    #pragma unroll
    for (int i=0;i<4;i++){
      int e = er0 + i;
      float cf = pp[i] + bxv;
      int d = dI[e];
      atomicAdd(&agg_x[(size_t)d*3+0], relS[e][0]*cf);
      atomicAdd(&agg_x[(size_t)d*3+1], relS[e][1]*cf);
      atomicAdd(&agg_x[(size_t)d*3+2], relS[e][2]*cf);
    }
  }
  __syncthreads();

  {
    int j = tid & 127, half = tid >> 7;
    int eb = half*32;
    float sacc = 0.f; int run = dI[eb];
    for (int e = eb; e < eb+32; e++){
      int d = dI[e];
      if (d != run){ atomicAdd(&agg_m[(size_t)run*H + j], sacc); sacc = 0.f; run = d; }
      sacc += m2_lds[e][j];
    }
    atomicAdd(&agg_m[(size_t)run*H + j], sacc);
  }
}

// ---------------- node update via bf16 MFMA ----------------
// 128 threads (2 waves), 32 nodes/block; wave owns 16 nodes, all 128 cols.
__global__ __launch_bounds__(128, 3) void k_node_mfma(
    float* __restrict__ h, unsigned short* __restrict__ hbm, float* __restrict__ x,
    const float* __restrict__ agg_m, const float* __restrict__ agg_x,
    const int* __restrict__ degi,
    const unsigned short* __restrict__ Wh1p, const float* __restrict__ bh1,
    const unsigned short* __restrict__ Wh2p, const float* __restrict__ bh2,
    int N)
{
  __shared__ __align__(16) unsigned short u_lds[128*36]; // u1 bf16 col-major [k2][row], stride 36

  int tid = threadIdx.x;
  int nb0 = blockIdx.x * 32;

  if (tid < 96){
    int nn = tid/3, cc = tid - nn*3;
    int gn = nb0 + nn;
    if (gn < N){
      float dv = (float)degi[gn]; if (dv < 1.f) dv = 1.f;
      x[(size_t)gn*3 + cc] += agg_x[(size_t)gn*3 + cc] / dv;
    }
  }

  int lane = tid & 63, wave = tid >> 6;
  int c = lane & 15, q = lane >> 4;
  int node = nb0 + wave*16 + c;
  int na = node < N ? node : N-1;

  // A frags: ks 0..3 = h (bf16 mirror), ks 4..7 = agg_m (fp32 -> bf16)
  s8 af[8];
  #pragma unroll
  for (int ks=0; ks<4; ks++)
    af[ks] = *(const s8*)(hbm + (size_t)na*H + ks*32 + q*8);
  #pragma unroll
  for (int ks=4; ks<8; ks++){
    const float* am = agg_m + (size_t)na*H + (ks-4)*32 + q*8;
    f4 a0 = *(const f4*)am, a1 = *(const f4*)(am+4);
    s8 p;
    #pragma unroll
    for (int jj=0;jj<4;jj++){ p[jj] = (short)f2bf(a0[jj]); p[4+jj] = (short)f2bf(a1[jj]); }
    af[ks] = p;
  }

  f32x4 acc[8];
  #pragma unroll
  for (int t=0;t<8;t++) acc[t] = (f32x4){0.f,0.f,0.f,0.f};
  const s8* B1 = (const s8*)Wh1p;
  #pragma unroll
  for (int ks=0; ks<8; ks++){
    const s8* bp = B1 + (ks*8)*64 + lane;
    #pragma unroll
    for (int t=0;t<8;t++)
      acc[t] = __builtin_amdgcn_mfma_f32_16x16x32_bf16(af[ks], bp[t*64], acc[t], 0,0,0);
  }

  int er0 = wave*16 + 4*q;
  #pragma unroll
  for (int t=0;t<8;t++){
    int j2 = 16*t + c;
    float b1 = bh1[j2];
    s4 mv;
    #pragma unroll
    for (int i=0;i<4;i++) mv[i] = (short)f2bf(silu_f(acc[t][i] + b1));
    *(s4*)&u_lds[36*j2 + er0] = mv;   // wave-private rows: no barrier needed
  }

  f32x4 acc2[8];
  #pragma unroll
  for (int t=0;t<8;t++) acc2[t] = (f32x4){0.f,0.f,0.f,0.f};
  const s8* B2 = (const s8*)Wh2p;
  #pragma unroll
  for (int ks=0; ks<4; ks++){
    s8 a2;
    int base = 36*(32*ks + 8*q) + wave*16 + c;
    #pragma unroll
    for (int j=0;j<8;j++) a2[j] = (short)u_lds[base + 36*j];
    const s8* bp = B2 + (ks*8)*64 + lane;
    #pragma unroll
    for (int t=0;t<8;t++)
      acc2[t] = __builtin_amdgcn_mfma_f32_16x16x32_bf16(a2, bp[t*64], acc2[t], 0,0,0);
  }

  // epilogue: h += upd (residual), refresh bf16 mirror
  #pragma unroll
  for (int t=0;t<8;t++){
    int j2 = 16*t + c;
    float b2 = bh2[j2];
    #pragma unroll
    for (int i=0;i<4;i++){
      int gr = nb0 + wave*16 + 4*q + i;
      if (gr < N){
        size_t off = (size_t)gr*H + j2;
        float hv = h[off] + acc2[t][i] + b2;
        h[off] = hv;
        hbm[off] = f2bf(hv);
      }
    }
  }
}

// ---------------- NextType head via bf16 MFMA ----------------
// t1[n,f,:] = silu(h[n,:] @ W1f[f] + bd1), W1f[f][k][j]=(Wl[f,k]+bl[k])*Wd1[k,j]
// 128 threads (2 waves), 32 nodes/block.
__global__ __launch_bounds__(128, 3) void k_head3(
    const unsigned short* __restrict__ hb, const int* __restrict__ batch,
    const unsigned short* __restrict__ W1p, const float* __restrict__ bd1,
    const unsigned short* __restrict__ Wd2p, const float* __restrict__ bd2,
    const float* __restrict__ Wd3, const float* __restrict__ bd3,
    float* __restrict__ agg, int N)
{
  __shared__ __align__(16) unsigned short t1tr[96*36]; // t1 bf16 col-major [k2][row], stride 36
  __shared__ float t3s[32][18];
  __shared__ float lgs[32][18];
  __shared__ int bI[32];

  int tid = threadIdx.x;
  int nb0 = blockIdx.x * 32;
  int lane = tid & 63, wave = tid >> 6;
  int c = lane & 15, q = lane >> 4;

  int node = nb0 + wave*16 + c;
  int na = node < N ? node : N-1;

  // A frags for h (K=128)
  s8 ah[4];
  #pragma unroll
  for (int ks=0; ks<4; ks++)
    ah[ks] = *(const s8*)(hb + (size_t)na*H + ks*32 + q*8);

  // per-lane column constants
  float b1c[6];
  #pragma unroll
  for (int t=0;t<6;t++){ int col=16*t+c; b1c[t] = (col<85) ? bd1[col] : 0.f; }
  float b2c[3], w3c[3];
  #pragma unroll
  for (int t=0;t<3;t++){
    int col=16*t+c;
    b2c[t] = (col<43) ? bd2[col] : 0.f;
    w3c[t] = (col<43) ? Wd3[col] : 0.f;
  }
  float bd3v = bd3[0];
  int er0 = wave*16 + 4*q;

  for (int f=0; f<16; f++){
    const s8* B1 = (const s8*)W1p + f*(W1FS/8);
    f32x4 acc[6];
    #pragma unroll
    for (int t=0;t<6;t++) acc[t] = (f32x4){0.f,0.f,0.f,0.f};
    #pragma unroll
    for (int ks=0; ks<4; ks++){
      #pragma unroll
      for (int t=0;t<6;t++)
        acc[t] = __builtin_amdgcn_mfma_f32_16x16x32_bf16(ah[ks], B1[(ks*6+t)*64+lane], acc[t], 0,0,0);
    }
    // silu + transpose to LDS (wave-private rows; cols>=85 are exact zeros)
    #pragma unroll
    for (int t=0;t<6;t++){
      int j2 = 16*t + c;
      s4 mv;
      #pragma unroll
      for (int i=0;i<4;i++) mv[i] = (short)f2bf(silu_f(acc[t][i] + b1c[t]));
      *(s4*)&t1tr[36*j2 + er0] = mv;
    }
    // layer 2: t2 = silu(t1 @ Wd2 + bd2), K=96 (zero-padded)
    f32x4 acc2[3];
    #pragma unroll
    for (int t=0;t<3;t++) acc2[t] = (f32x4){0.f,0.f,0.f,0.f};
    const s8* B2 = (const s8*)Wd2p;
    #pragma unroll
    for (int ks=0; ks<3; ks++){
      s8 a2;
      int base = 36*(32*ks + 8*q) + wave*16 + c;
      #pragma unroll
      for (int j=0;j<8;j++) a2[j] = (short)t1tr[base + 36*j];
      #pragma unroll
      for (int t=0;t<3;t++)
        acc2[t] = __builtin_amdgcn_mfma_f32_16x16x32_bf16(a2, B2[(ks*3+t)*64+lane], acc2[t], 0,0,0);
    }
    // layer 3: t3 = t2 @ Wd3 + bd3 (reduce over 16 col-lanes)
    float pp[4] = {0.f,0.f,0.f,0.f};
    #pragma unroll
    for (int t=0;t<3;t++){
      #pragma unroll
      for (int i=0;i<4;i++) pp[i] += silu_f(acc2[t][i] + b2c[t]) * w3c[t];
    }
    #pragma unroll
    for (int off=1; off<16; off<<=1){
      #pragma unroll
      for (int i=0;i<4;i++) pp[i] += __shfl_xor(pp[i], off, 64);
    }
    if (c == 0){
      #pragma unroll
      for (int i=0;i<4;i++) t3s[wave*16 + 4*q + i][f] = pp[i] + bd3v;
    }
  }
  __syncthreads();

  // per-node log-softmax over 16 types
  if (tid < 32){
    int n = nb0 + tid;
    bool valid = n < N;
    bI[tid] = batch[valid ? n : (N-1)];
    if (valid){
      float m = t3s[tid][0];
      #pragma unroll
      for (int i=1;i<16;i++) m = fmaxf(m, t3s[tid][i]);
      float s = 0.f;
      #pragma unroll
      for (int i=0;i<16;i++) s += __expf(t3s[tid][i] - m);
      float ls = __logf(s);
      #pragma unroll
      for (int i=0;i<16;i++) lgs[tid][i] = t3s[tid][i] - m - ls;
    } else {
      #pragma unroll
      for (int i=0;i<16;i++) lgs[tid][i] = 0.f;
    }
  }
  __syncthreads();

  // segmented batch reduction (nodes sorted by batch) -> few atomics
  if (tid < 16){
    int f = tid;
    float acc = 0.f; int run = bI[0];
    for (int n = 0; n < 32; n++){
      int b = bI[n];
      if (b != run){ atomicAdd(&agg[run*16 + f], acc); acc = 0.f; run = b; }
      acc += lgs[n][f];
    }
    atomicAdd(&agg[run*16 + f], acc);
  }
}

// ---------------- final: out = agg - logsumexp(agg) ----------------
__global__ void k_final(const float* __restrict__ agg, float* __restrict__ out){
  int tid = threadIdx.x; // 128 threads: b = tid>>4, f = tid&15
  float vv = agg[tid];
  float m = vv;
  #pragma unroll
  for (int off = 1; off < 16; off <<= 1) m = fmaxf(m, __shfl_xor(m, off, 64));
  float s = __expf(vv - m);
  #pragma unroll
  for (int off = 1; off < 16; off <<= 1) s += __shfl_xor(s, off, 64);
  out[tid] = vv - m - __logf(s);
}

extern "C" void kernel_launch(void* const* d_in, const int* in_sizes, int n_in,
                              void* d_out, int out_size, void* d_ws, size_t ws_size,
                              hipStream_t stream)
{
  const float* ligand_x   = (const float*)d_in[0];
  const float* pocket_x   = (const float*)d_in[1];
  const float* ligand_pos = (const float*)d_in[2];
  const float* pocket_pos = (const float*)d_in[3];
  const float* Wl_emb = (const float*)d_in[4];
  const float* bl_emb = (const float*)d_in[5];
  const float* Wp_emb = (const float*)d_in[6];
  const float* bp_emb = (const float*)d_in[7];
  const float* We1 = (const float*)d_in[8];
  const float* be1 = (const float*)d_in[9];
  const float* We2 = (const float*)d_in[10];
  const float* be2 = (const float*)d_in[11];
  const float* Wx  = (const float*)d_in[12];
  const float* bx  = (const float*)d_in[13];
  const float* Wh1 = (const float*)d_in[14];
  const float* bh1 = (const float*)d_in[15];
  const float* Wh2 = (const float*)d_in[16];
  const float* bh2 = (const float*)d_in[17];
  const float* Wd1 = (const float*)d_in[18];
  const float* bd1 = (const float*)d_in[19];
  const float* Wd2 = (const float*)d_in[20];
  const float* bd2 = (const float*)d_in[21];
  const float* Wd3 = (const float*)d_in[22];
  const float* bd3 = (const float*)d_in[23];
  const int* l2l    = (const int*)d_in[24];
  const int* p2p    = (const int*)d_in[25];
  const int* lbatch = (const int*)d_in[26];

  char* w = (char*)d_ws;
  auto alloc = [&](size_t bytes)->char*{
    char* p = w; w += (bytes + 255) & ~(size_t)255; return p;
  };
  float* hl    = (float*)alloc((size_t)NLIG*H*4);
  float* hp    = (float*)alloc((size_t)NPOC*H*4);
  unsigned short* hbl = (unsigned short*)alloc((size_t)NLIG*H*2);
  unsigned short* hbp = (unsigned short*)alloc((size_t)NPOC*H*2);
  float* xl    = (float*)alloc((size_t)NLIG*3*4);
  float* xp    = (float*)alloc((size_t)NPOC*3*4);
  float* agg_m = (float*)alloc((size_t)NPOC*H*4);
  float* agg_x = (float*)alloc((size_t)NPOC*3*4);
  int* deg_l = (int*)alloc((size_t)NLIG*4);
  int* deg_p = (int*)alloc((size_t)NPOC*4);
  int* offs_l = (int*)alloc((size_t)(NLIG+1)*4);
  int* offs_p = (int*)alloc((size_t)(NPOC+1)*4);
  int* cur_l = (int*)alloc((size_t)NLIG*4);
  int* cur_p = (int*)alloc((size_t)NPOC*4);
  int* ssrc_l = (int*)alloc((size_t)ELIG*4);
  int* sdst_l = (int*)alloc((size_t)ELIG*4);
  int* ssrc_p = (int*)alloc((size_t)EPOC*4);
  int* sdst_p = (int*)alloc((size_t)EPOC*4);
  unsigned short* We1p = (unsigned short*)alloc((size_t)6*G1S*2);
  unsigned short* We2p = (unsigned short*)alloc((size_t)6*G2S*2);
  unsigned short* Wh1p = (unsigned short*)alloc((size_t)6*G1S*2);
  unsigned short* Wh2p = (unsigned short*)alloc((size_t)6*G2S*2);
  unsigned short* W1p  = (unsigned short*)alloc((size_t)16*W1FS*2);
  unsigned short* Wd2p = (unsigned short*)alloc((size_t)WD2S*2);
  float* aggB = (float*)alloc((size_t)NB*16*4);

  hipMemsetAsync(deg_l, 0, (size_t)NLIG*4, stream);
  hipMemsetAsync(deg_p, 0, (size_t)NPOC*4, stream);
  hipMemsetAsync(cur_l, 0, (size_t)NLIG*4, stream);
  hipMemsetAsync(cur_p, 0, (size_t)NPOC*4, stream);
  hipMemsetAsync(aggB, 0, (size_t)NB*16*4, stream);
  hipMemcpyAsync(xl, ligand_pos, (size_t)NLIG*3*4, hipMemcpyDeviceToDevice, stream);
  hipMemcpyAsync(xp, pocket_pos, (size_t)NPOC*3*4, hipMemcpyDeviceToDevice, stream);

  k_embed<<<NLIG/2, 256, 0, stream>>>(ligand_x, Wl_emb, bl_emb, hl, hbl, NLIG, FLIG);
  k_embed<<<NPOC/2, 256, 0, stream>>>(pocket_x, Wp_emb, bp_emb, hp, hbp, NPOC, FPOC);

  const int* lsrc = l2l;          const int* ldst = l2l + ELIG;
  const int* psrc = p2p;          const int* pdst = p2p + EPOC;

  k_hist<<<(ELIG+255)/256, 256, 0, stream>>>(ldst, deg_l, ELIG);
  k_hist<<<(EPOC+255)/256, 256, 0, stream>>>(pdst, deg_p, EPOC);
  k_scan<<<1, 1024, 0, stream>>>(deg_l, offs_l, NLIG, ELIG);
  k_scan<<<1, 1024, 0, stream>>>(deg_p, offs_p, NPOC, EPOC);
  k_sort<<<(ELIG+255)/256, 256, 0, stream>>>(lsrc, ldst, offs_l, cur_l, ssrc_l, sdst_l, ELIG);
  k_sort<<<(EPOC+255)/256, 256, 0, stream>>>(psrc, pdst, offs_p, cur_p, ssrc_p, sdst_p, EPOC);
  {
    int npack = 6*G1S + 6*G2S + 6*G1S + 6*G2S + 16*W1FS + WD2S;
    k_pack<<<(npack+255)/256, 256, 0, stream>>>(We1, We2, Wh1, Wh2,
        Wl_emb, bl_emb, Wd1, Wd2, We1p, We2p, Wh1p, Wh2p, W1p, Wd2p);
  }

  for (int l = 0; l < NLAYERS; l++){
    // ---- ligand (g = 0) ----
    {
      int gl = 0*NLAYERS + l;
      hipMemsetAsync(agg_m, 0, (size_t)NLIG*H*4, stream);
      hipMemsetAsync(agg_x, 0, (size_t)NLIG*3*4, stream);
      k_edge_mfma<<<ELIG/64, 256, 0, stream>>>(hbl, xl, ssrc_l, sdst_l,
          We1p + (size_t)gl*G1S, We1 + (size_t)gl*257*H + 256*H, be1 + (size_t)gl*H,
          We2p + (size_t)gl*G2S, be2 + (size_t)gl*H,
          Wx  + (size_t)gl*H,    bx  + gl,
          agg_m, agg_x);
      k_node_mfma<<<(NLIG+31)/32, 128, 0, stream>>>(hl, hbl, xl, agg_m, agg_x, deg_l,
          Wh1p + (size_t)gl*G1S, bh1 + (size_t)gl*H,
          Wh2p + (size_t)gl*G2S, bh2 + (size_t)gl*H, NLIG);
    }
    // ---- pocket (g = 1) ----
    {
      int gl = 1*NLAYERS + l;
      hipMemsetAsync(agg_m, 0, (size_t)NPOC*H*4, stream);
      hipMemsetAsync(agg_x, 0, (size_t)NPOC*3*4, stream);
      k_edge_mfma<<<EPOC/64, 256, 0, stream>>>(hbp, xp, ssrc_p, sdst_p,
          We1p + (size_t)gl*G1S, We1 + (size_t)gl*257*H + 256*H, be1 + (size_t)gl*H,
          We2p + (size_t)gl*G2S, be2 + (size_t)gl*H,
          Wx  + (size_t)gl*H,    bx  + gl,
          agg_m, agg_x);
      k_node_mfma<<<(NPOC+31)/32, 128, 0, stream>>>(hp, hbp, xp, agg_m, agg_x, deg_p,
          Wh1p + (size_t)gl*G1S, bh1 + (size_t)gl*H,
          Wh2p + (size_t)gl*G2S, bh2 + (size_t)gl*H, NPOC);
    }
  }

  k_head3<<<(NLIG+31)/32, 128, 0, stream>>>(hbl, lbatch, W1p, bd1, Wd2p, bd2,
                                            Wd3, bd3, aggB, NLIG);
  k_final<<<1, 128, 0, stream>>>(aggB, (float*)d_out);
}

// Round 4
// 810.326 us; speedup vs baseline: 4.3060x; 1.2669x over previous
//
#include <hip/hip_runtime.h>
#include <hip/hip_bf16.h>
#include <math.h>

typedef __attribute__((ext_vector_type(4))) float f4;
typedef __attribute__((ext_vector_type(4))) float f32x4;
typedef __attribute__((ext_vector_type(8))) short s8;
typedef __attribute__((ext_vector_type(4))) short s4;

#define H 128
#define NLAYERS 3
#define FLIG 16
#define FPOC 27
#define NLIG 20000
#define NPOC 30000
#define ELIG 160000
#define EPOC 240000
#define NB 8

#define NBLK_EL (ELIG/64)        // 2500
#define NBLK_EP (EPOC/64)        // 3750
#define NBLK_NL ((NLIG+31)/32)   // 625
#define NBLK_NP ((NPOC+31)/32)   // 938

// packed-weight strides (elements)
#define G1S (8*8*64*8)   // K=256 GEMM1 weights per group (8 ksteps x 8 coltiles)
#define G2S (4*8*64*8)   // K=128 GEMM2 weights per group
#define W1FS (4*6*64*8)  // head W1f per f: 4 ksteps x 6 coltiles
#define WD2S (3*3*64*8)  // head Wd2: 3 ksteps x 3 coltiles

__device__ __forceinline__ float silu_f(float v){ return v / (1.0f + __expf(-v)); }
__device__ __forceinline__ unsigned short f2bf(float v){
  __hip_bfloat16 b = __float2bfloat16(v);
  return *reinterpret_cast<unsigned short*>(&b);
}

// ---------------- fused embedding (both graphs) + position copy ----------------
__global__ void k_embed2(const float* __restrict__ lx, const float* __restrict__ px,
                         const float* __restrict__ lpos, const float* __restrict__ ppos,
                         const float* __restrict__ Wl, const float* __restrict__ bl,
                         const float* __restrict__ Wp, const float* __restrict__ bp,
                         float* __restrict__ hl, unsigned short* __restrict__ hbl,
                         float* __restrict__ hp, unsigned short* __restrict__ hbp,
                         float* __restrict__ xl, float* __restrict__ xp){
  int bid = blockIdx.x;
  int g = (bid < NLIG/2) ? 0 : 1;
  int nb = (g ? bid - NLIG/2 : bid) * 2;
  const float* x  = g ? px : lx;
  const float* W  = g ? Wp : Wl;
  const float* b  = g ? bp : bl;
  float* h = g ? hp : hl;
  unsigned short* hb = g ? hbp : hbl;
  int F = g ? FPOC : FLIG;
  int tid = threadIdx.x;
  int n = nb + (tid >> 7);
  int j = tid & 127;
  float acc = b[j];
  for (int k = 0; k < F; k++) acc += x[n*F + k] * W[k*H + j];
  h[(size_t)n*H + j] = acc;
  hb[(size_t)n*H + j] = f2bf(acc);
  if (tid < 6){
    const float* pos = g ? ppos : lpos;
    float* xd = g ? xp : xl;
    xd[(size_t)nb*3 + tid] = pos[(size_t)nb*3 + tid];
  }
}

// ---------------- fused degree histogram ----------------
__global__ void k_hist2(const int* __restrict__ ldst, const int* __restrict__ pdst,
                        int* __restrict__ deg_l, int* __restrict__ deg_p){
  int e = blockIdx.x*256 + threadIdx.x;
  if (e < ELIG) atomicAdd(&deg_l[ldst[e]], 1);
  else if (e < ELIG+EPOC) atomicAdd(&deg_p[pdst[e-ELIG]], 1);
}

// ---------------- both exclusive scans, one dispatch ----------------
__global__ void k_scan2(const int* __restrict__ deg_l, int* __restrict__ offs_l,
                        const int* __restrict__ deg_p, int* __restrict__ offs_p){
  __shared__ int part[1024];
  const int* deg = blockIdx.x ? deg_p : deg_l;
  int* offs = blockIdx.x ? offs_p : offs_l;
  int N = blockIdx.x ? NPOC : NLIG;
  int E = blockIdx.x ? EPOC : ELIG;
  int t = threadIdx.x;
  int chunk = (N + 1023) >> 10;
  int b0 = t*chunk;
  int b1 = b0 + chunk; if (b1 > N) b1 = N;
  int s = 0;
  for (int i = b0; i < b1; i++) s += deg[i];
  part[t] = s;
  __syncthreads();
  for (int off = 1; off < 1024; off <<= 1){
    int v = (t >= off) ? part[t-off] : 0;
    __syncthreads();
    part[t] += v;
    __syncthreads();
  }
  int run = part[t] - s;
  for (int i = b0; i < b1; i++){ offs[i] = run; run += deg[i]; }
  if (t == 1023) offs[N] = E;
}

// ---------------- fused counting-sort scatter ----------------
__global__ void k_sort2(const int* __restrict__ lsrc, const int* __restrict__ ldst,
                        const int* __restrict__ psrc, const int* __restrict__ pdst,
                        const int* __restrict__ offs_l, const int* __restrict__ offs_p,
                        int* __restrict__ cur_l, int* __restrict__ cur_p,
                        int* __restrict__ ssrc_l, int* __restrict__ sdst_l,
                        int* __restrict__ ssrc_p, int* __restrict__ sdst_p){
  int e = blockIdx.x*256 + threadIdx.x;
  if (e < ELIG){
    int d = ldst[e];
    int p = offs_l[d] + atomicAdd(&cur_l[d], 1);
    ssrc_l[p] = lsrc[e]; sdst_l[p] = d;
  } else if (e < ELIG+EPOC){
    int ee = e - ELIG;
    int d = pdst[ee];
    int p = offs_p[d] + atomicAdd(&cur_p[d], 1);
    ssrc_p[p] = psrc[ee]; sdst_p[p] = d;
  }
}

// ---------------- weight packer: MFMA fragment order, fp32 -> bf16 ----------------
__global__ void k_pack(const float* __restrict__ We1, const float* __restrict__ We2,
                       const float* __restrict__ Wh1, const float* __restrict__ Wh2,
                       const float* __restrict__ Wl, const float* __restrict__ bl,
                       const float* __restrict__ Wd1, const float* __restrict__ Wd2,
                       unsigned short* __restrict__ We1p, unsigned short* __restrict__ We2p,
                       unsigned short* __restrict__ Wh1p, unsigned short* __restrict__ Wh2p,
                       unsigned short* __restrict__ W1p, unsigned short* __restrict__ Wd2p)
{
  int idx = blockIdx.x*256 + threadIdx.x;
  const int nWe1 = 6*G1S, nWe2 = 6*G2S, nWh1 = 6*G1S, nWh2 = 6*G2S, nW1 = 16*W1FS, nWd2 = WD2S;
  int i = idx;
  if (i < nWe1){
    int j = i&7, l = (i>>3)&63, t = (i>>9)&7, ks = (i>>12)&7, g = i>>15;
    int k = 32*ks + 8*(l>>4) + j, col = 16*t + (l&15);
    We1p[i] = f2bf(We1[((size_t)g*257 + k)*H + col]);
    return;
  }
  i -= nWe1;
  if (i < nWe2){
    int j = i&7, l = (i>>3)&63, t = (i>>9)&7, ks = (i>>12)&3, g = i>>14;
    int k = 32*ks + 8*(l>>4) + j, col = 16*t + (l&15);
    We2p[i] = f2bf(We2[((size_t)g*H + k)*H + col]);
    return;
  }
  i -= nWe2;
  if (i < nWh1){
    int j = i&7, l = (i>>3)&63, t = (i>>9)&7, ks = (i>>12)&7, g = i>>15;
    int k = 32*ks + 8*(l>>4) + j, col = 16*t + (l&15);
    Wh1p[i] = f2bf(Wh1[((size_t)g*256 + k)*H + col]);
    return;
  }
  i -= nWh1;
  if (i < nWh2){
    int j = i&7, l = (i>>3)&63, t = (i>>9)&7, ks = (i>>12)&3, g = i>>14;
    int k = 32*ks + 8*(l>>4) + j, col = 16*t + (l&15);
    Wh2p[i] = f2bf(Wh2[((size_t)g*H + k)*H + col]);
    return;
  }
  i -= nWh2;
  if (i < nW1){
    int f = i / W1FS, r = i % W1FS;
    int ks = r / (6*512), r2 = r % (6*512);
    int t = r2 / 512, l = (r2 % 512) >> 3, j = r2 & 7;
    int k = 32*ks + 8*(l>>4) + j, col = 16*t + (l&15);
    float v = 0.f;
    if (col < 85) v = (Wl[f*H + k] + bl[k]) * Wd1[k*85 + col];
    W1p[i] = f2bf(v);
    return;
  }
  i -= nW1;
  if (i < nWd2){
    int ks = i / (3*512), r2 = i % (3*512);
    int t = r2 / 512, l = (r2 % 512) >> 3, j = r2 & 7;
    int k = 32*ks + 8*(l>>4) + j, col = 16*t + (l&15);
    float v = 0.f;
    if (k < 85 && col < 43) v = Wd2[k*43 + col];
    Wd2p[i] = f2bf(v);
  }
}

// ---------------- fused edge MLP (bf16 MFMA), both graphs, low-LDS ----------------
__global__ __launch_bounds__(256, 4) void k_edge_f(
    const unsigned short* __restrict__ hb_l, const unsigned short* __restrict__ hb_p,
    const float* __restrict__ x_l, const float* __restrict__ x_p,
    const int* __restrict__ ssrc_l, const int* __restrict__ sdst_l,
    const int* __restrict__ ssrc_p, const int* __restrict__ sdst_p,
    const unsigned short* __restrict__ We1pb, const float* __restrict__ We1b,
    const float* __restrict__ be1b,
    const unsigned short* __restrict__ We2pb, const float* __restrict__ be2b,
    const float* __restrict__ Wxb, const float* __restrict__ bxb,
    float* __restrict__ agg_m_l, float* __restrict__ agg_x_l,
    float* __restrict__ agg_m_p, float* __restrict__ agg_x_p,
    int layer)
{
  __shared__ __align__(16) unsigned short m_lds[128*70]; // 17920B; overlaid by m2b (fp32 [64][66])
  __shared__ float relS[64][3];
  __shared__ float xsS[64][3];
  __shared__ float d2S[64];
  __shared__ int sI[64], dI[64];
  float* m2b = (float*)m_lds;

  int tid = threadIdx.x;
  int bid = blockIdx.x;
  int g = (bid < NBLK_EL) ? 0 : 1;
  int e0 = (g ? bid - NBLK_EL : bid) * 64;
  const unsigned short* hb = g ? hb_p : hb_l;
  const float* x = g ? x_p : x_l;
  const int* ssrc = g ? ssrc_p : ssrc_l;
  const int* sdst = g ? sdst_p : sdst_l;
  float* agg_m = g ? agg_m_p : agg_m_l;
  float* agg_x = g ? agg_x_p : agg_x_l;
  int gl = g*NLAYERS + layer;
  const unsigned short* We1p = We1pb + (size_t)gl*G1S;
  const unsigned short* We2p = We2pb + (size_t)gl*G2S;
  const float* We1r256 = We1b + ((size_t)gl*257 + 256)*H;
  const float* be1 = be1b + (size_t)gl*H;
  const float* be2 = be2b + (size_t)gl*H;
  const float* Wx = Wxb + (size_t)gl*H;

  if (tid < 64){ sI[tid] = ssrc[e0+tid]; dI[tid] = sdst[e0+tid]; }
  __syncthreads();

  int lane = tid & 63, wave = tid >> 6;
  int c = lane & 15, q = lane >> 4;
  int eA = wave*16 + c;
  size_t rowD = (size_t)dI[eA]*H, rowS = (size_t)sI[eA]*H;
  const unsigned short* pD = hb + rowD + q*8;
  const unsigned short* pS = hb + rowS + q*8;

  // issue A-frag gathers early (overlap with x-gather + barriers)
  s8 afr[8];
  #pragma unroll
  for (int ks=0; ks<8; ks++)
    afr[ks] = *(const s8*)((ks<4) ? (pD + ks*32) : (pS + (ks-4)*32));

  if (tid < 128){
    int e = tid & 63, side = tid >> 6;
    int row = side ? sI[e] : dI[e];
    float v0 = x[row*3+0], v1 = x[row*3+1], v2 = x[row*3+2];
    if (side){ xsS[e][0]=v0; xsS[e][1]=v1; xsS[e][2]=v2; }
    else     { relS[e][0]=v0; relS[e][1]=v1; relS[e][2]=v2; }
  }
  __syncthreads();
  if (tid < 64){
    float rx = relS[tid][0]-xsS[tid][0];
    float ry = relS[tid][1]-xsS[tid][1];
    float rz = relS[tid][2]-xsS[tid][2];
    relS[tid][0]=rx; relS[tid][1]=ry; relS[tid][2]=rz;
    d2S[tid] = rx*rx+ry*ry+rz*rz;
  }
  // d2S visibility barrier is the post-GEMM1 one below

  // ---- GEMM1 ----
  f32x4 acc[8];
  #pragma unroll
  for (int t=0;t<8;t++) acc[t] = (f32x4){0.f,0.f,0.f,0.f};
  const s8* B1 = (const s8*)We1p;
  #pragma unroll
  for (int ks=0; ks<8; ks++){
    const s8* bp = B1 + (ks*8)*64 + lane;
    #pragma unroll
    for (int t=0;t<8;t++)
      acc[t] = __builtin_amdgcn_mfma_f32_16x16x32_bf16(afr[ks], bp[t*64], acc[t], 0,0,0);
  }
  __syncthreads();   // d2S/relS ready for all; m_lds about to be written

  int er0 = wave*16 + 4*q;
  float d2v[4];
  #pragma unroll
  for (int i=0;i<4;i++) d2v[i] = d2S[er0+i];
  #pragma unroll
  for (int t=0;t<8;t++){
    int j2 = 16*t + c;
    float w256 = We1r256[j2], bias = be1[j2];
    s4 mv;
    #pragma unroll
    for (int i=0;i<4;i++){
      float v = silu_f(acc[t][i] + d2v[i]*w256 + bias);
      mv[i] = (short)f2bf(v);
    }
    *(s4*)&m_lds[70*j2 + er0] = mv;
  }
  __syncthreads();

  // ---- GEMM2 ----
  f32x4 acc2[8];
  #pragma unroll
  for (int t=0;t<8;t++) acc2[t] = (f32x4){0.f,0.f,0.f,0.f};
  const s8* B2 = (const s8*)We2p;
  #pragma unroll
  for (int ks=0; ks<4; ks++){
    s8 a2;
    int base = 70*(32*ks + 8*q) + wave*16 + c;
    #pragma unroll
    for (int j=0;j<8;j++) a2[j] = (short)m_lds[base + 70*j];
    const s8* bp = B2 + (ks*8)*64 + lane;
    #pragma unroll
    for (int t=0;t<8;t++)
      acc2[t] = __builtin_amdgcn_mfma_f32_16x16x32_bf16(a2, bp[t*64], acc2[t], 0,0,0);
  }
  __syncthreads();   // all m_lds reads done; safe to overlay with m2b

  // epilogue pass 0: silu all, coef partials, stash cols 0..63 fp32
  float pp[4] = {0.f,0.f,0.f,0.f};
  float sv_hi[4][4];
  #pragma unroll
  for (int t=0;t<8;t++){
    int j2 = 16*t + c;
    float b2v = be2[j2], wxv = Wx[j2];
    #pragma unroll
    for (int i=0;i<4;i++){
      float v = silu_f(acc2[t][i] + b2v);
      pp[i] += v * wxv;
      if (t < 4) m2b[(er0+i)*66 + j2] = v;
      else       sv_hi[t-4][i] = v;
    }
  }
  #pragma unroll
  for (int off=1; off<16; off<<=1){
    #pragma unroll
    for (int i=0;i<4;i++) pp[i] += __shfl_xor(pp[i], off, 64);
  }
  if (c == 0){
    float bxv = bxb[gl];
    #pragma unroll
    for (int i=0;i<4;i++){
      int e = er0 + i;
      float cf = pp[i] + bxv;
      int d = dI[e];
      atomicAdd(&agg_x[(size_t)d*3+0], relS[e][0]*cf);
      atomicAdd(&agg_x[(size_t)d*3+1], relS[e][1]*cf);
      atomicAdd(&agg_x[(size_t)d*3+2], relS[e][2]*cf);
    }
  }
  __syncthreads();

  // scatter pass 0 (cols 0..63): 256 threads, 16 edges each, segmented by dst
  {
    int col = tid & 63, qq = tid >> 6, eb = qq*16;
    float sacc = 0.f; int run = dI[eb];
    for (int e = eb; e < eb+16; e++){
      int d = dI[e];
      if (d != run){ atomicAdd(&agg_m[(size_t)run*H + col], sacc); sacc = 0.f; run = d; }
      sacc += m2b[e*66 + col];
    }
    atomicAdd(&agg_m[(size_t)run*H + col], sacc);
  }
  __syncthreads();

  // epilogue pass 1: stash cols 64..127
  #pragma unroll
  for (int t=4;t<8;t++){
    int j2 = 16*t + c;
    #pragma unroll
    for (int i=0;i<4;i++) m2b[(er0+i)*66 + (j2-64)] = sv_hi[t-4][i];
  }
  __syncthreads();

  // scatter pass 1 (cols 64..127)
  {
    int col = tid & 63, qq = tid >> 6, eb = qq*16;
    float sacc = 0.f; int run = dI[eb];
    for (int e = eb; e < eb+16; e++){
      int d = dI[e];
      if (d != run){ atomicAdd(&agg_m[(size_t)run*H + col + 64], sacc); sacc = 0.f; run = d; }
      sacc += m2b[e*66 + col];
    }
    atomicAdd(&agg_m[(size_t)run*H + col + 64], sacc);
  }
}

// ---------------- fused node update (bf16 MFMA), both graphs, zeroes agg ----------------
__global__ __launch_bounds__(128, 3) void k_node_f(
    float* __restrict__ h_l, unsigned short* __restrict__ hb_l, float* __restrict__ x_l,
    float* __restrict__ h_p, unsigned short* __restrict__ hb_p, float* __restrict__ x_p,
    float* __restrict__ agg_m_l, float* __restrict__ agg_x_l,
    float* __restrict__ agg_m_p, float* __restrict__ agg_x_p,
    const int* __restrict__ deg_l, const int* __restrict__ deg_p,
    const unsigned short* __restrict__ Wh1pb, const float* __restrict__ bh1b,
    const unsigned short* __restrict__ Wh2pb, const float* __restrict__ bh2b,
    int layer)
{
  __shared__ __align__(16) unsigned short u_lds[128*36];

  int tid = threadIdx.x;
  int bid = blockIdx.x;
  int g = (bid < NBLK_NL) ? 0 : 1;
  int nb0 = (g ? bid - NBLK_NL : bid) * 32;
  int N = g ? NPOC : NLIG;
  float* h = g ? h_p : h_l;
  unsigned short* hbm = g ? hb_p : hb_l;
  float* x = g ? x_p : x_l;
  float* agg_m = g ? agg_m_p : agg_m_l;
  float* agg_x = g ? agg_x_p : agg_x_l;
  const int* degi = g ? deg_p : deg_l;
  int gl = g*NLAYERS + layer;
  const unsigned short* Wh1p = Wh1pb + (size_t)gl*G1S;
  const unsigned short* Wh2p = Wh2pb + (size_t)gl*G2S;
  const float* bh1 = bh1b + (size_t)gl*H;
  const float* bh2 = bh2b + (size_t)gl*H;

  if (tid < 96){
    int nn = tid/3, cc = tid - nn*3;
    int gn = nb0 + nn;
    if (gn < N){
      float dv = (float)degi[gn]; if (dv < 1.f) dv = 1.f;
      x[(size_t)gn*3 + cc] += agg_x[(size_t)gn*3 + cc] / dv;
      agg_x[(size_t)gn*3 + cc] = 0.f;   // reset for next layer / next call
    }
  }

  int lane = tid & 63, wave = tid >> 6;
  int c = lane & 15, q = lane >> 4;
  int node = nb0 + wave*16 + c;
  int na = node < N ? node : N-1;

  // A frags: ks 0..3 = h (bf16 mirror), ks 4..7 = agg_m (fp32 -> bf16), then zero agg_m
  s8 af[8];
  #pragma unroll
  for (int ks=0; ks<4; ks++)
    af[ks] = *(const s8*)(hbm + (size_t)na*H + ks*32 + q*8);
  #pragma unroll
  for (int ks=4; ks<8; ks++){
    const float* am = agg_m + (size_t)na*H + (ks-4)*32 + q*8;
    f4 a0 = *(const f4*)am, a1 = *(const f4*)(am+4);
    s8 p;
    #pragma unroll
    for (int jj=0;jj<4;jj++){ p[jj] = (short)f2bf(a0[jj]); p[4+jj] = (short)f2bf(a1[jj]); }
    af[ks] = p;
  }
  if (node < N){
    f4 z4 = (f4){0.f,0.f,0.f,0.f};
    #pragma unroll
    for (int ks=0; ks<4; ks++){
      float* am = agg_m + (size_t)na*H + ks*32 + q*8;
      *(f4*)am = z4; *(f4*)(am+4) = z4;
    }
  }

  f32x4 acc[8];
  #pragma unroll
  for (int t=0;t<8;t++) acc[t] = (f32x4){0.f,0.f,0.f,0.f};
  const s8* B1 = (const s8*)Wh1p;
  #pragma unroll
  for (int ks=0; ks<8; ks++){
    const s8* bp = B1 + (ks*8)*64 + lane;
    #pragma unroll
    for (int t=0;t<8;t++)
      acc[t] = __builtin_amdgcn_mfma_f32_16x16x32_bf16(af[ks], bp[t*64], acc[t], 0,0,0);
  }

  int er0 = wave*16 + 4*q;
  #pragma unroll
  for (int t=0;t<8;t++){
    int j2 = 16*t + c;
    float b1 = bh1[j2];
    s4 mv;
    #pragma unroll
    for (int i=0;i<4;i++) mv[i] = (short)f2bf(silu_f(acc[t][i] + b1));
    *(s4*)&u_lds[36*j2 + er0] = mv;   // wave-private rows
  }

  f32x4 acc2[8];
  #pragma unroll
  for (int t=0;t<8;t++) acc2[t] = (f32x4){0.f,0.f,0.f,0.f};
  const s8* B2 = (const s8*)Wh2p;
  #pragma unroll
  for (int ks=0; ks<4; ks++){
    s8 a2;
    int base = 36*(32*ks + 8*q) + wave*16 + c;
    #pragma unroll
    for (int j=0;j<8;j++) a2[j] = (short)u_lds[base + 36*j];
    const s8* bp = B2 + (ks*8)*64 + lane;
    #pragma unroll
    for (int t=0;t<8;t++)
      acc2[t] = __builtin_amdgcn_mfma_f32_16x16x32_bf16(a2, bp[t*64], acc2[t], 0,0,0);
  }

  #pragma unroll
  for (int t=0;t<8;t++){
    int j2 = 16*t + c;
    float b2 = bh2[j2];
    #pragma unroll
    for (int i=0;i<4;i++){
      int gr = nb0 + wave*16 + 4*q + i;
      if (gr < N){
        size_t off = (size_t)gr*H + j2;
        float hv = h[off] + acc2[t][i] + b2;
        h[off] = hv;
        hbm[off] = f2bf(hv);
      }
    }
  }
}

// ---------------- NextType head via bf16 MFMA ----------------
__global__ __launch_bounds__(128, 3) void k_head3(
    const unsigned short* __restrict__ hb, const int* __restrict__ batch,
    const unsigned short* __restrict__ W1p, const float* __restrict__ bd1,
    const unsigned short* __restrict__ Wd2p, const float* __restrict__ bd2,
    const float* __restrict__ Wd3, const float* __restrict__ bd3,
    float* __restrict__ agg, int N)
{
  __shared__ __align__(16) unsigned short t1tr[96*36];
  __shared__ float t3s[32][18];
  __shared__ float lgs[32][18];
  __shared__ int bI[32];

  int tid = threadIdx.x;
  int nb0 = blockIdx.x * 32;
  int lane = tid & 63, wave = tid >> 6;
  int c = lane & 15, q = lane >> 4;

  int node = nb0 + wave*16 + c;
  int na = node < N ? node : N-1;

  s8 ah[4];
  #pragma unroll
  for (int ks=0; ks<4; ks++)
    ah[ks] = *(const s8*)(hb + (size_t)na*H + ks*32 + q*8);

  float b1c[6];
  #pragma unroll
  for (int t=0;t<6;t++){ int col=16*t+c; b1c[t] = (col<85) ? bd1[col] : 0.f; }
  float b2c[3], w3c[3];
  #pragma unroll
  for (int t=0;t<3;t++){
    int col=16*t+c;
    b2c[t] = (col<43) ? bd2[col] : 0.f;
    w3c[t] = (col<43) ? Wd3[col] : 0.f;
  }
  float bd3v = bd3[0];
  int er0 = wave*16 + 4*q;

  for (int f=0; f<16; f++){
    const s8* B1 = (const s8*)W1p + f*(W1FS/8);
    f32x4 acc[6];
    #pragma unroll
    for (int t=0;t<6;t++) acc[t] = (f32x4){0.f,0.f,0.f,0.f};
    #pragma unroll
    for (int ks=0; ks<4; ks++){
      #pragma unroll
      for (int t=0;t<6;t++)
        acc[t] = __builtin_amdgcn_mfma_f32_16x16x32_bf16(ah[ks], B1[(ks*6+t)*64+lane], acc[t], 0,0,0);
    }
    #pragma unroll
    for (int t=0;t<6;t++){
      int j2 = 16*t + c;
      s4 mv;
      #pragma unroll
      for (int i=0;i<4;i++) mv[i] = (short)f2bf(silu_f(acc[t][i] + b1c[t]));
      *(s4*)&t1tr[36*j2 + er0] = mv;
    }
    f32x4 acc2[3];
    #pragma unroll
    for (int t=0;t<3;t++) acc2[t] = (f32x4){0.f,0.f,0.f,0.f};
    const s8* B2 = (const s8*)Wd2p;
    #pragma unroll
    for (int ks=0; ks<3; ks++){
      s8 a2;
      int base = 36*(32*ks + 8*q) + wave*16 + c;
      #pragma unroll
      for (int j=0;j<8;j++) a2[j] = (short)t1tr[base + 36*j];
      #pragma unroll
      for (int t=0;t<3;t++)
        acc2[t] = __builtin_amdgcn_mfma_f32_16x16x32_bf16(a2, B2[(ks*3+t)*64+lane], acc2[t], 0,0,0);
    }
    float pp[4] = {0.f,0.f,0.f,0.f};
    #pragma unroll
    for (int t=0;t<3;t++){
      #pragma unroll
      for (int i=0;i<4;i++) pp[i] += silu_f(acc2[t][i] + b2c[t]) * w3c[t];
    }
    #pragma unroll
    for (int off=1; off<16; off<<=1){
      #pragma unroll
      for (int i=0;i<4;i++) pp[i] += __shfl_xor(pp[i], off, 64);
    }
    if (c == 0){
      #pragma unroll
      for (int i=0;i<4;i++) t3s[wave*16 + 4*q + i][f] = pp[i] + bd3v;
    }
  }
  __syncthreads();

  if (tid < 32){
    int n = nb0 + tid;
    bool valid = n < N;
    bI[tid] = batch[valid ? n : (N-1)];
    if (valid){
      float m = t3s[tid][0];
      #pragma unroll
      for (int i=1;i<16;i++) m = fmaxf(m, t3s[tid][i]);
      float s = 0.f;
      #pragma unroll
      for (int i=0;i<16;i++) s += __expf(t3s[tid][i] - m);
      float ls = __logf(s);
      #pragma unroll
      for (int i=0;i<16;i++) lgs[tid][i] = t3s[tid][i] - m - ls;
    } else {
      #pragma unroll
      for (int i=0;i<16;i++) lgs[tid][i] = 0.f;
    }
  }
  __syncthreads();

  if (tid < 16){
    int f = tid;
    float acc = 0.f; int run = bI[0];
    for (int n = 0; n < 32; n++){
      int b = bI[n];
      if (b != run){ atomicAdd(&agg[run*16 + f], acc); acc = 0.f; run = b; }
      acc += lgs[n][f];
    }
    atomicAdd(&agg[run*16 + f], acc);
  }
}

// ---------------- final: out = agg - logsumexp(agg) ----------------
__global__ void k_final(const float* __restrict__ agg, float* __restrict__ out){
  int tid = threadIdx.x;
  float vv = agg[tid];
  float m = vv;
  #pragma unroll
  for (int off = 1; off < 16; off <<= 1) m = fmaxf(m, __shfl_xor(m, off, 64));
  float s = __expf(vv - m);
  #pragma unroll
  for (int off = 1; off < 16; off <<= 1) s += __shfl_xor(s, off, 64);
  out[tid] = vv - m - __logf(s);
}

extern "C" void kernel_launch(void* const* d_in, const int* in_sizes, int n_in,
                              void* d_out, int out_size, void* d_ws, size_t ws_size,
                              hipStream_t stream)
{
  const float* ligand_x   = (const float*)d_in[0];
  const float* pocket_x   = (const float*)d_in[1];
  const float* ligand_pos = (const float*)d_in[2];
  const float* pocket_pos = (const float*)d_in[3];
  const float* Wl_emb = (const float*)d_in[4];
  const float* bl_emb = (const float*)d_in[5];
  const float* Wp_emb = (const float*)d_in[6];
  const float* bp_emb = (const float*)d_in[7];
  const float* We1 = (const float*)d_in[8];
  const float* be1 = (const float*)d_in[9];
  const float* We2 = (const float*)d_in[10];
  const float* be2 = (const float*)d_in[11];
  const float* Wx  = (const float*)d_in[12];
  const float* bx  = (const float*)d_in[13];
  const float* Wh1 = (const float*)d_in[14];
  const float* bh1 = (const float*)d_in[15];
  const float* Wh2 = (const float*)d_in[16];
  const float* bh2 = (const float*)d_in[17];
  const float* Wd1 = (const float*)d_in[18];
  const float* bd1 = (const float*)d_in[19];
  const float* Wd2 = (const float*)d_in[20];
  const float* bd2 = (const float*)d_in[21];
  const float* Wd3 = (const float*)d_in[22];
  const float* bd3 = (const float*)d_in[23];
  const int* l2l    = (const int*)d_in[24];
  const int* p2p    = (const int*)d_in[25];
  const int* lbatch = (const int*)d_in[26];

  char* w = (char*)d_ws;
  auto alloc = [&](size_t bytes)->char*{
    char* p = w; w += (bytes + 255) & ~(size_t)255; return p;
  };
  float* hl    = (float*)alloc((size_t)NLIG*H*4);
  float* hp    = (float*)alloc((size_t)NPOC*H*4);
  unsigned short* hbl = (unsigned short*)alloc((size_t)NLIG*H*2);
  unsigned short* hbp = (unsigned short*)alloc((size_t)NPOC*H*2);
  float* xl    = (float*)alloc((size_t)NLIG*3*4);
  float* xp    = (float*)alloc((size_t)NPOC*3*4);
  int* offs_l = (int*)alloc((size_t)(NLIG+1)*4);
  int* offs_p = (int*)alloc((size_t)(NPOC+1)*4);
  int* ssrc_l = (int*)alloc((size_t)ELIG*4);
  int* sdst_l = (int*)alloc((size_t)ELIG*4);
  int* ssrc_p = (int*)alloc((size_t)EPOC*4);
  int* sdst_p = (int*)alloc((size_t)EPOC*4);
  unsigned short* We1p = (unsigned short*)alloc((size_t)6*G1S*2);
  unsigned short* We2p = (unsigned short*)alloc((size_t)6*G2S*2);
  unsigned short* Wh1p = (unsigned short*)alloc((size_t)6*G1S*2);
  unsigned short* Wh2p = (unsigned short*)alloc((size_t)6*G2S*2);
  unsigned short* W1p  = (unsigned short*)alloc((size_t)16*W1FS*2);
  unsigned short* Wd2p = (unsigned short*)alloc((size_t)WD2S*2);
  // ---- contiguous zero-init region ----
  char* zbase = w;
  int* deg_l = (int*)alloc((size_t)NLIG*4);
  int* deg_p = (int*)alloc((size_t)NPOC*4);
  int* cur_l = (int*)alloc((size_t)NLIG*4);
  int* cur_p = (int*)alloc((size_t)NPOC*4);
  float* aggB = (float*)alloc((size_t)NB*16*4);
  float* agg_m_l = (float*)alloc((size_t)NLIG*H*4);
  float* agg_x_l = (float*)alloc((size_t)NLIG*3*4);
  float* agg_m_p = (float*)alloc((size_t)NPOC*H*4);
  float* agg_x_p = (float*)alloc((size_t)NPOC*3*4);
  size_t zsize = (size_t)(w - zbase);

  hipMemsetAsync(zbase, 0, zsize, stream);

  const int* lsrc = l2l;          const int* ldst = l2l + ELIG;
  const int* psrc = p2p;          const int* pdst = p2p + EPOC;

  k_embed2<<<NLIG/2 + NPOC/2, 256, 0, stream>>>(ligand_x, pocket_x, ligand_pos, pocket_pos,
      Wl_emb, bl_emb, Wp_emb, bp_emb, hl, hbl, hp, hbp, xl, xp);
  k_hist2<<<(ELIG+EPOC+255)/256, 256, 0, stream>>>(ldst, pdst, deg_l, deg_p);
  k_scan2<<<2, 1024, 0, stream>>>(deg_l, offs_l, deg_p, offs_p);
  k_sort2<<<(ELIG+EPOC+255)/256, 256, 0, stream>>>(lsrc, ldst, psrc, pdst,
      offs_l, offs_p, cur_l, cur_p, ssrc_l, sdst_l, ssrc_p, sdst_p);
  {
    int npack = 6*G1S + 6*G2S + 6*G1S + 6*G2S + 16*W1FS + WD2S;
    k_pack<<<(npack+255)/256, 256, 0, stream>>>(We1, We2, Wh1, Wh2,
        Wl_emb, bl_emb, Wd1, Wd2, We1p, We2p, Wh1p, Wh2p, W1p, Wd2p);
  }

  for (int l = 0; l < NLAYERS; l++){
    k_edge_f<<<NBLK_EL + NBLK_EP, 256, 0, stream>>>(hbl, hbp, xl, xp,
        ssrc_l, sdst_l, ssrc_p, sdst_p,
        We1p, We1, be1, We2p, be2, Wx, bx,
        agg_m_l, agg_x_l, agg_m_p, agg_x_p, l);
    k_node_f<<<NBLK_NL + NBLK_NP, 128, 0, stream>>>(hl, hbl, xl, hp, hbp, xp,
        agg_m_l, agg_x_l, agg_m_p, agg_x_p, deg_l, deg_p,
        Wh1p, bh1, Wh2p, bh2, l);
  }

  k_head3<<<(NLIG+31)/32, 128, 0, stream>>>(hbl, lbatch, W1p, bd1, Wd2p, bd2,
                                            Wd3, bd3, aggB, NLIG);
  k_final<<<1, 128, 0, stream>>>(aggB, (float*)d_out);
}